// Round 1
// baseline (931.865 us; speedup 1.0000x reference)
//
#include <hip/hip_runtime.h>
#include <math.h>

// GAT pipeline, all f32.
// Stages: GEMM1 (z = h@W1cat^T, [N,256]) -> per-node attn scores -> CSR build
// (hist/scan/scatter) -> fused GAT1 (softmax-aggregate 4 heads + ELU + 256->64
// matvec -> z2 + layer2 scores) -> GAT2 (global sum of alpha*z2[src]) ->
// fractal gather-sum -> tiny finalize producing the 64-float mean output.
// Workspace ~140 MB.

#define CAP 128   // per-wave LDS cache of edge list; deg>CAP falls back to global recompute

__device__ __forceinline__ float wred_max(float v){
#pragma unroll
  for (int o = 1; o < 64; o <<= 1) v = fmaxf(v, __shfl_xor(v, o, 64));
  return v;
}
__device__ __forceinline__ float wred_sum(float v){
#pragma unroll
  for (int o = 1; o < 64; o <<= 1) v += __shfl_xor(v, o, 64);
  return v;
}
__device__ __forceinline__ float lrelu(float x){ return x >= 0.f ? x : 0.01f*x; }

// ---------------- GEMM1: z[N,256] = h[N,128] @ W1^T  (W1 = layer1_fc as [256,128])
__global__ __launch_bounds__(256) void k_gemm1(const float* __restrict__ h,
    const float* __restrict__ W, float* __restrict__ z, int N)
{
  __shared__ __align__(16) float As[16][68];  // [k][m], pad 68 -> fp4-aligned, 2-way-only conflicts
  __shared__ __align__(16) float Bs[16][68];  // [k][n]
  const int tid = threadIdx.x;
  const int tx = tid & 15, ty = tid >> 4;
  const int m0 = blockIdx.x * 64, n0 = blockIdx.y * 64;
  const int lr = tid >> 2;          // 0..63
  const int lk = (tid & 3) << 2;    // 0,4,8,12
  float acc[4][4] = {};
  for (int kk = 0; kk < 128; kk += 16){
    float4 av = make_float4(0.f,0.f,0.f,0.f);
    int row = m0 + lr;
    if (row < N) av = *(const float4*)&h[row*128 + kk + lk];
    As[lk+0][lr]=av.x; As[lk+1][lr]=av.y; As[lk+2][lr]=av.z; As[lk+3][lr]=av.w;
    float4 bv = *(const float4*)&W[(n0+lr)*128 + kk + lk];
    Bs[lk+0][lr]=bv.x; Bs[lk+1][lr]=bv.y; Bs[lk+2][lr]=bv.z; Bs[lk+3][lr]=bv.w;
    __syncthreads();
#pragma unroll
    for (int k = 0; k < 16; k++){
      float4 a4 = *(const float4*)&As[k][ty*4];
      float4 b4 = *(const float4*)&Bs[k][tx*4];
      float a[4] = {a4.x,a4.y,a4.z,a4.w};
      float b[4] = {b4.x,b4.y,b4.z,b4.w};
#pragma unroll
      for (int i=0;i<4;i++)
#pragma unroll
        for (int j=0;j<4;j++) acc[i][j] += a[i]*b[j];
    }
    __syncthreads();
  }
#pragma unroll
  for (int i=0;i<4;i++){
    int row = m0 + ty*4 + i;
    if (row < N)
      *(float4*)&z[row*256 + n0 + tx*4] = make_float4(acc[i][0],acc[i][1],acc[i][2],acc[i][3]);
  }
}

// ---------------- per-node attention scores for layer1: s1src/s1dst [N][4]
__global__ __launch_bounds__(256) void k_scores1(const float* __restrict__ z,
    const float* __restrict__ a1, float* __restrict__ ssrc, float* __restrict__ sdst, int N)
{
  int i = blockIdx.x*256 + threadIdx.x;
  if (i >= N*4) return;
  int n = i >> 2, hh = i & 3;
  const float* zr = z + n*256 + hh*64;
  const float* as = a1 + hh*128;
  const float* ad = as + 64;
  float s0 = 0.f, s1 = 0.f;
#pragma unroll
  for (int d = 0; d < 64; d += 4){
    float4 zv = *(const float4*)&zr[d];
    float4 av = *(const float4*)&as[d];
    float4 dv = *(const float4*)&ad[d];
    s0 += zv.x*av.x + zv.y*av.y + zv.z*av.z + zv.w*av.w;
    s1 += zv.x*dv.x + zv.y*dv.y + zv.z*dv.z + zv.w*dv.w;
  }
  ssrc[i] = s0; sdst[i] = s1;
}

// ---------------- CSR build
__global__ void k_hist(const int* __restrict__ d, int* __restrict__ deg, int E){
  int i = blockIdx.x*256 + threadIdx.x;
  if (i < E) atomicAdd(&deg[d[i]], 1);
}
__global__ __launch_bounds__(256) void k_scan1(const int* __restrict__ deg, int* __restrict__ part){
  __shared__ int tmp[256];
  int t = threadIdx.x;
  tmp[t] = deg[blockIdx.x*256 + t];
  __syncthreads();
  for (int off = 128; off > 0; off >>= 1){
    if (t < off) tmp[t] += tmp[t+off];
    __syncthreads();
  }
  if (t == 0) part[blockIdx.x] = tmp[0];
}
__global__ __launch_bounds__(512) void k_scan2(int* __restrict__ part, int B){
  __shared__ int tmp[512];
  int t = threadIdx.x;
  int v = (t < B) ? part[t] : 0;
  tmp[t] = v; __syncthreads();
  for (int off = 1; off < 512; off <<= 1){
    int x = (t >= off) ? tmp[t-off] : 0;
    __syncthreads();
    tmp[t] += x;
    __syncthreads();
  }
  if (t < B) part[t] = tmp[t] - v;   // exclusive
}
__global__ __launch_bounds__(256) void k_scan3(const int* __restrict__ deg, const int* __restrict__ part,
    int* __restrict__ rowptr, int* __restrict__ cursor){
  __shared__ int tmp[256];
  int t = threadIdx.x, i = blockIdx.x*256 + t;
  int v = deg[i];
  tmp[t] = v; __syncthreads();
  for (int off = 1; off < 256; off <<= 1){
    int x = (t >= off) ? tmp[t-off] : 0;
    __syncthreads();
    tmp[t] += x;
    __syncthreads();
  }
  int excl = tmp[t] - v + part[blockIdx.x];
  rowptr[i] = excl; cursor[i] = excl;
}
__global__ void k_scatter(const int* __restrict__ s, const int* __restrict__ d,
    int* __restrict__ cursor, int* __restrict__ csr, int E){
  int i = blockIdx.x*256 + threadIdx.x;
  if (i < E){
    int p = atomicAdd(&cursor[d[i]], 1);
    csr[p] = s[i];
  }
}

// ---------------- layer2_fc repack: w2p[k4*256 + lane*4 + i] = fc[lane][k4*4+i]
__global__ void k_w2p(const float* __restrict__ fc, float* __restrict__ w2p){
  int t = blockIdx.x*256 + threadIdx.x;
  if (t < 64*256){
    int k4 = t >> 8, r = t & 255, l = r >> 2, i = r & 3;
    w2p[t] = fc[l*256 + k4*4 + i];
  }
}

// ---------------- fused layer1 GAT (4 heads) + ELU + 256->64 matvec + layer2 scores
__global__ __launch_bounds__(256) void k_gat1(
    const float* __restrict__ z, const float* __restrict__ s1src, const float* __restrict__ s1dst,
    const int* __restrict__ rowptr, const int* __restrict__ csr,
    const float* __restrict__ w2p, const float* __restrict__ a2,
    float* __restrict__ z2, float* __restrict__ s2src, float* __restrict__ s2dst, int N)
{
  __shared__ __align__(16) float hnei[4][256];
  __shared__ int   sbuf[4][CAP];
  __shared__ __align__(16) float4 ebuf[4][CAP];
  const int wave = threadIdx.x >> 6, lane = threadIdx.x & 63;
  const int dst = blockIdx.x*4 + wave;
  const bool act = dst < N;
  if (act){
    const int beg = rowptr[dst];
    const int deg = rowptr[dst+1] - beg;
    const float4 sd = *(const float4*)&s1dst[dst*4];
    // pass1: e per edge (4 heads packed), running max
    float m0=-INFINITY, m1=-INFINITY, m2=-INFINITY, m3=-INFINITY;
    for (int j = lane; j < deg; j += 64){
      int s = csr[beg+j];
      float4 sv = *(const float4*)&s1src[s*4];
      float4 e;
      e.x = lrelu(sv.x+sd.x); e.y = lrelu(sv.y+sd.y);
      e.z = lrelu(sv.z+sd.z); e.w = lrelu(sv.w+sd.w);
      if (j < CAP){ sbuf[wave][j] = s; ebuf[wave][j] = e; }
      m0 = fmaxf(m0,e.x); m1 = fmaxf(m1,e.y); m2 = fmaxf(m2,e.z); m3 = fmaxf(m3,e.w);
    }
    m0 = wred_max(m0); m1 = wred_max(m1); m2 = wred_max(m2); m3 = wred_max(m3);
    // pass2: denominators
    float t0=0.f,t1=0.f,t2=0.f,t3=0.f;
    for (int j = lane; j < deg; j += 64){
      float4 e;
      if (j < CAP) e = ebuf[wave][j];
      else {
        int s = csr[beg+j];
        float4 sv = *(const float4*)&s1src[s*4];
        e.x = lrelu(sv.x+sd.x); e.y = lrelu(sv.y+sd.y);
        e.z = lrelu(sv.z+sd.z); e.w = lrelu(sv.w+sd.w);
      }
      t0 += __expf(e.x-m0); t1 += __expf(e.y-m1); t2 += __expf(e.z-m2); t3 += __expf(e.w-m3);
    }
    const float i0 = 1.f/wred_sum(t0), i1 = 1.f/wred_sum(t1);
    const float i2 = 1.f/wred_sum(t2), i3 = 1.f/wred_sum(t3);
    // pass3: weighted aggregation of z[src] rows; lane = dim, sequential edges (uniform)
    float a0=0.f,a1=0.f,a2v=0.f,a3=0.f;
    const float* zb = z + lane;
#pragma unroll 2
    for (int j = 0; j < deg; j++){
      int s; float4 e;
      if (j < CAP){ s = sbuf[wave][j]; e = ebuf[wave][j]; }
      else {
        s = csr[beg+j];
        float4 sv = *(const float4*)&s1src[s*4];
        e.x = lrelu(sv.x+sd.x); e.y = lrelu(sv.y+sd.y);
        e.z = lrelu(sv.z+sd.z); e.w = lrelu(sv.w+sd.w);
      }
      const float* zr = zb + s*256;
      float al0 = __expf(e.x-m0)*i0, al1 = __expf(e.y-m1)*i1;
      float al2 = __expf(e.z-m2)*i2, al3 = __expf(e.w-m3)*i3;
      a0  += al0*zr[0];   a1 += al1*zr[64];
      a2v += al2*zr[128]; a3 += al3*zr[192];
    }
    // ELU + stage in LDS
    hnei[wave][lane]     = a0  > 0.f ? a0  : expm1f(a0);
    hnei[wave][64+lane]  = a1  > 0.f ? a1  : expm1f(a1);
    hnei[wave][128+lane] = a2v > 0.f ? a2v : expm1f(a2v);
    hnei[wave][192+lane] = a3  > 0.f ? a3  : expm1f(a3);
  }
  __syncthreads();
  if (act){
    // z2[dst] = layer2_fc @ hnei   (lane = output dim)
    float zv = 0.f;
#pragma unroll 8
    for (int k4 = 0; k4 < 64; k4++){
      float4 hv = *(const float4*)&hnei[wave][k4*4];
      float4 wv = *(const float4*)&w2p[k4*256 + lane*4];
      zv += hv.x*wv.x + hv.y*wv.y + hv.z*wv.z + hv.w*wv.w;
    }
    z2[dst*64 + lane] = zv;
    float ss = wred_sum(zv * a2[lane]);
    float sd2 = wred_sum(zv * a2[64+lane]);
    if (lane == 0){ s2src[dst] = ss; s2dst[dst] = sd2; }
  }
}

// ---------------- layer2 GAT, reduced straight to the global sum
__global__ __launch_bounds__(256) void k_gat2(
    const float* __restrict__ z2, const float* __restrict__ s2src, const float* __restrict__ s2dst,
    const int* __restrict__ rowptr, const int* __restrict__ csr,
    float* __restrict__ accOut, int N)
{
  __shared__ int   sbuf[4][CAP];
  __shared__ float ebuf[4][CAP];
  __shared__ float red[4][64];
  const int wave = threadIdx.x >> 6, lane = threadIdx.x & 63;
  float g = 0.f;
  const int stride = gridDim.x * 4;
  for (int dst = blockIdx.x*4 + wave; dst < N; dst += stride){
    int beg = rowptr[dst], deg = rowptr[dst+1] - beg;
    float sd = s2dst[dst];
    float mx = -INFINITY;
    for (int j = lane; j < deg; j += 64){
      int s = csr[beg+j];
      float e = lrelu(s2src[s] + sd);
      if (j < CAP){ sbuf[wave][j] = s; ebuf[wave][j] = e; }
      mx = fmaxf(mx, e);
    }
    float m = wred_max(mx);
    float ts = 0.f;
    for (int j = lane; j < deg; j += 64){
      float e = (j < CAP) ? ebuf[wave][j] : lrelu(s2src[csr[beg+j]] + sd);
      ts += __expf(e - m);
    }
    float inv = 1.f/wred_sum(ts);
#pragma unroll 4
    for (int j = 0; j < deg; j++){
      int s; float e;
      if (j < CAP){ s = sbuf[wave][j]; e = ebuf[wave][j]; }
      else { s = csr[beg+j]; e = lrelu(s2src[s] + sd); }
      g += __expf(e - m)*inv * z2[s*64 + lane];
    }
  }
  red[wave][lane] = g;
  __syncthreads();
  if (wave == 0)
    atomicAdd(&accOut[lane], red[0][lane]+red[1][lane]+red[2][lane]+red[3][lane]);
}

// ---------------- fractal: acc[s][k] = sum_n h[fcm[n,s]][k]
__global__ __launch_bounds__(256) void k_frac(const float* __restrict__ h,
    const int* __restrict__ fcm, float* __restrict__ accFrac, int N)
{
  __shared__ float red[4][6][64];
  const int wave = threadIdx.x >> 6, lane = threadIdx.x & 63;
  float a[6] = {0.f,0.f,0.f,0.f,0.f,0.f};
  const int stride = gridDim.x * 4;
  for (int n = blockIdx.x*4 + wave; n < N; n += stride){
    int i0 = fcm[n*3], i1 = fcm[n*3+1], i2 = fcm[n*3+2];
    a[0] += h[i0*128 + lane]; a[1] += h[i0*128 + 64 + lane];
    a[2] += h[i1*128 + lane]; a[3] += h[i1*128 + 64 + lane];
    a[4] += h[i2*128 + lane]; a[5] += h[i2*128 + 64 + lane];
  }
#pragma unroll
  for (int q = 0; q < 6; q++) red[wave][q][lane] = a[q];
  __syncthreads();
  if (wave == 0){
#pragma unroll
    for (int q = 0; q < 6; q++){
      float v = red[0][q][lane]+red[1][q][lane]+red[2][q][lane]+red[3][q][lane];
      atomicAdd(&accFrac[(q>>1)*128 + (q&1)*64 + lane], v);
    }
  }
}

// ---------------- finalize: tiny matvecs on the two 64/384-float accumulators
__global__ __launch_bounds__(256) void k_finalize(const float* __restrict__ acc,
    const float* __restrict__ frw, const float* __restrict__ frf,
    const float* __restrict__ fc2, float* __restrict__ out, float invN)
{
  __shared__ float g[384], mm[192], hfrac[64], nei[64];
  int t = threadIdx.x;
  for (int i = t; i < 384; i += 256) g[i] = acc[64 + i] * invN;
  if (t < 64) nei[t] = acc[t] * invN;
  __syncthreads();
  for (int i = t; i < 192; i += 256){
    int s = i >> 6, d = i & 63;
    const float* w = frw + (s*64 + d)*128;
    const float* gs = g + s*128;
    float sum = 0.f;
    for (int k = 0; k < 128; k++) sum += gs[k]*w[k];
    mm[i] = sum;
  }
  __syncthreads();
  if (t < 64){
    float s = 0.f;
    for (int k = 0; k < 192; k++) s += mm[k]*frf[t*192 + k];
    hfrac[t] = s;
  }
  __syncthreads();
  if (t < 64){
    float o = 0.f;
    for (int k = 0; k < 64; k++)
      o += fc2[t*128 + k]*nei[k] + fc2[t*128 + 64 + k]*hfrac[k];
    out[t] = o;
  }
}

extern "C" void kernel_launch(void* const* d_in, const int* in_sizes, int n_in,
                              void* d_out, int out_size, void* d_ws, size_t ws_size,
                              hipStream_t stream)
{
  const float* h    = (const float*)d_in[0];
  const int*   srcI = (const int*)  d_in[1];
  const int*   dstI = (const int*)  d_in[2];
  const int*   fcm  = (const int*)  d_in[3];
  const float* l1fc = (const float*)d_in[4];
  const float* l1at = (const float*)d_in[5];
  const float* l2fc = (const float*)d_in[6];
  const float* l2at = (const float*)d_in[7];
  const float* frw  = (const float*)d_in[8];
  const float* frf  = (const float*)d_in[9];
  const float* fc2  = (const float*)d_in[10];
  float* out = (float*)d_out;
  (void)n_in; (void)out_size; (void)ws_size;

  const int N = in_sizes[0] / 128;
  const int E = in_sizes[1];
  const int B = (N + 256) / 256;     // ceil((N+1)/256) so rowptr[N] is covered
  const int PAD = B * 256;

  char* w = (char*)d_ws;
  size_t off = 0;
  auto alloc = [&](size_t bytes) -> char* {
    char* p = w + off; off = (off + bytes + 255) & ~(size_t)255; return p;
  };
  float* z    = (float*)alloc((size_t)N*256*4);   // 102.4 MB
  float* z2   = (float*)alloc((size_t)N*64*4);    // 25.6 MB
  float* s1s  = (float*)alloc((size_t)N*4*4);
  float* s1d  = (float*)alloc((size_t)N*4*4);
  float* s2s  = (float*)alloc((size_t)N*4);
  float* s2d  = (float*)alloc((size_t)N*4);
  int*   deg    = (int*)alloc((size_t)PAD*4);
  int*   rowptr = (int*)alloc((size_t)PAD*4);
  int*   cursor = (int*)alloc((size_t)PAD*4);
  int*   part   = (int*)alloc(512*4);
  int*   csr    = (int*)alloc((size_t)E*4);       // 6.8 MB
  float* w2p    = (float*)alloc(16384*4);
  float* acc    = (float*)alloc(448*4);           // [0:64) nei2-sum, [64:448) frac-sum

  hipMemsetAsync(deg, 0, (size_t)PAD*4, stream);
  hipMemsetAsync(acc, 0, 448*4, stream);

  hipLaunchKernelGGL(k_w2p,     dim3(64),              dim3(256), 0, stream, l2fc, w2p);
  hipLaunchKernelGGL(k_gemm1,   dim3((N+63)/64, 4),    dim3(256), 0, stream, h, l1fc, z, N);
  hipLaunchKernelGGL(k_scores1, dim3((N*4+255)/256),   dim3(256), 0, stream, z, l1at, s1s, s1d, N);
  hipLaunchKernelGGL(k_hist,    dim3((E+255)/256),     dim3(256), 0, stream, dstI, deg, E);
  hipLaunchKernelGGL(k_scan1,   dim3(B),               dim3(256), 0, stream, deg, part);
  hipLaunchKernelGGL(k_scan2,   dim3(1),               dim3(512), 0, stream, part, B);
  hipLaunchKernelGGL(k_scan3,   dim3(B),               dim3(256), 0, stream, deg, part, rowptr, cursor);
  hipLaunchKernelGGL(k_scatter, dim3((E+255)/256),     dim3(256), 0, stream, srcI, dstI, cursor, csr, E);
  hipLaunchKernelGGL(k_gat1,    dim3((N+3)/4),         dim3(256), 0, stream,
                     z, s1s, s1d, rowptr, csr, w2p, l2at, z2, s2s, s2d, N);
  hipLaunchKernelGGL(k_gat2,    dim3(1024),            dim3(256), 0, stream,
                     z2, s2s, s2d, rowptr, csr, acc, N);
  hipLaunchKernelGGL(k_frac,    dim3(1024),            dim3(256), 0, stream, h, fcm, acc + 64, N);
  hipLaunchKernelGGL(k_finalize,dim3(1),               dim3(256), 0, stream,
                     acc, frw, frf, fc2, out, 1.0f/(float)N);
}

// Round 2
// 925.721 us; speedup vs baseline: 1.0066x; 1.0066x over previous
//
#include <hip/hip_runtime.h>
#include <math.h>

// GAT pipeline. z and z2 stored as bf16 (packed) to halve gather traffic;
// alphas precomputed into LDS so the aggregation pass is pure FMA + one
// dwordx2 load per lane per edge. Scores fused into the GEMM1 epilogue.

#define CAP 128   // per-wave LDS edge cache; deg>CAP falls back to recompute

typedef unsigned int  uint_t;
typedef unsigned short ushort_t;

__device__ __forceinline__ float wred_max(float v){
#pragma unroll
  for (int o = 1; o < 64; o <<= 1) v = fmaxf(v, __shfl_xor(v, o, 64));
  return v;
}
__device__ __forceinline__ float wred_sum(float v){
#pragma unroll
  for (int o = 1; o < 64; o <<= 1) v += __shfl_xor(v, o, 64);
  return v;
}
__device__ __forceinline__ float lrelu(float x){ return x >= 0.f ? x : 0.01f*x; }
__device__ __forceinline__ ushort_t f2b(float f){
  uint_t u = __float_as_uint(f);
  u = (u + 0x7FFFu + ((u >> 16) & 1u)) >> 16;   // RNE
  return (ushort_t)u;
}
__device__ __forceinline__ float b2f_lo(uint_t w){ return __uint_as_float(w << 16); }
__device__ __forceinline__ float b2f_hi(uint_t w){ return __uint_as_float(w & 0xFFFF0000u); }

// ---------------- GEMM1 fused: zb[N][64] uint2 (4 heads bf16 per dim) + layer1 scores
// block: 64 rows x 256 cols (all heads), 256 threads, acc[4][4heads][4]
__global__ __launch_bounds__(256) void k_gemm1f(const float* __restrict__ h,
    const float* __restrict__ W, const float* __restrict__ a1,
    uint2* __restrict__ zb, float* __restrict__ s1s, float* __restrict__ s1d, int N)
{
  __shared__ __align__(16) float As[16][72];    // [k][row]
  __shared__ __align__(16) float Bs[16][260];   // [k][col]
  __shared__ float a1s[512];
  const int t = threadIdx.x;
  const int tx = t & 15, ty = t >> 4;
  const int m0 = blockIdx.x * 64;
  if (t < 512) {} // (a1 is 512 floats)
  a1s[t] = a1[t];
  a1s[t + 256] = a1[t + 256];
  const int arow = t >> 2, alk = (t & 3) * 4;
  float acc[4][4][4] = {};
  for (int kk = 0; kk < 128; kk += 16){
    float4 av = make_float4(0.f,0.f,0.f,0.f);
    if (m0 + arow < N) av = *(const float4*)&h[(size_t)(m0+arow)*128 + kk + alk];
    As[alk+0][arow]=av.x; As[alk+1][arow]=av.y; As[alk+2][arow]=av.z; As[alk+3][arow]=av.w;
#pragma unroll
    for (int q = 0; q < 4; q++){
      float4 bv = *(const float4*)&W[(size_t)t*128 + kk + q*4];
      Bs[q*4+0][t]=bv.x; Bs[q*4+1][t]=bv.y; Bs[q*4+2][t]=bv.z; Bs[q*4+3][t]=bv.w;
    }
    __syncthreads();
#pragma unroll
    for (int k = 0; k < 16; k++){
      float4 a4 = *(const float4*)&As[k][ty*4];
      float ar[4] = {a4.x, a4.y, a4.z, a4.w};
#pragma unroll
      for (int hh = 0; hh < 4; hh++){
        float4 b4 = *(const float4*)&Bs[k][hh*64 + tx*4];
        float br[4] = {b4.x, b4.y, b4.z, b4.w};
#pragma unroll
        for (int i = 0; i < 4; i++)
#pragma unroll
          for (int j = 0; j < 4; j++) acc[i][hh][j] += ar[i]*br[j];
      }
    }
    __syncthreads();
  }
  // scores: s1[row][hh] = sum_d z * a1[hh][d] (src: d<64 -> a1s[hh*128+d]; dst: +64)
#pragma unroll
  for (int i = 0; i < 4; i++){
    const int row = m0 + ty*4 + i;
#pragma unroll
    for (int hh = 0; hh < 4; hh++){
      float ps = 0.f, pd = 0.f;
#pragma unroll
      for (int j = 0; j < 4; j++){
        float v = acc[i][hh][j];
        ps += v * a1s[hh*128 + tx*4 + j];
        pd += v * a1s[hh*128 + 64 + tx*4 + j];
      }
#pragma unroll
      for (int o = 1; o < 16; o <<= 1){
        ps += __shfl_xor(ps, o, 64);
        pd += __shfl_xor(pd, o, 64);
      }
      if (tx == 0 && row < N){ s1s[row*4+hh] = ps; s1d[row*4+hh] = pd; }
    }
  }
  // packed bf16 store: zb[row*64 + dim] = {h0|h1<<16, h2|h3<<16}
#pragma unroll
  for (int i = 0; i < 4; i++){
    const int row = m0 + ty*4 + i;
    if (row < N){
#pragma unroll
      for (int j = 0; j < 4; j++){
        uint_t w0 = (uint_t)f2b(acc[i][0][j]) | ((uint_t)f2b(acc[i][1][j]) << 16);
        uint_t w1 = (uint_t)f2b(acc[i][2][j]) | ((uint_t)f2b(acc[i][3][j]) << 16);
        zb[(size_t)row*64 + tx*4 + j] = make_uint2(w0, w1);
      }
    }
  }
}

// ---------------- CSR build
__global__ void k_hist(const int* __restrict__ d, int* __restrict__ deg, int E){
  int i = blockIdx.x*256 + threadIdx.x;
  if (i < E) atomicAdd(&deg[d[i]], 1);
}
__global__ __launch_bounds__(256) void k_scan1(const int* __restrict__ deg, int* __restrict__ part){
  __shared__ int tmp[256];
  int t = threadIdx.x;
  tmp[t] = deg[blockIdx.x*256 + t];
  __syncthreads();
  for (int off = 128; off > 0; off >>= 1){
    if (t < off) tmp[t] += tmp[t+off];
    __syncthreads();
  }
  if (t == 0) part[blockIdx.x] = tmp[0];
}
__global__ __launch_bounds__(512) void k_scan2(int* __restrict__ part, int B){
  __shared__ int tmp[512];
  int t = threadIdx.x;
  int v = (t < B) ? part[t] : 0;
  tmp[t] = v; __syncthreads();
  for (int off = 1; off < 512; off <<= 1){
    int x = (t >= off) ? tmp[t-off] : 0;
    __syncthreads();
    tmp[t] += x;
    __syncthreads();
  }
  if (t < B) part[t] = tmp[t] - v;   // exclusive
}
__global__ __launch_bounds__(256) void k_scan3(const int* __restrict__ deg, const int* __restrict__ part,
    int* __restrict__ rowptr, int* __restrict__ cursor){
  __shared__ int tmp[256];
  int t = threadIdx.x, i = blockIdx.x*256 + t;
  int v = deg[i];
  tmp[t] = v; __syncthreads();
  for (int off = 1; off < 256; off <<= 1){
    int x = (t >= off) ? tmp[t-off] : 0;
    __syncthreads();
    tmp[t] += x;
    __syncthreads();
  }
  int excl = tmp[t] - v + part[blockIdx.x];
  rowptr[i] = excl; cursor[i] = excl;
}
__global__ void k_scatter(const int* __restrict__ s, const int* __restrict__ d,
    int* __restrict__ cursor, int* __restrict__ csr, int E){
  int i = blockIdx.x*256 + threadIdx.x;
  if (i < E){
    int p = atomicAdd(&cursor[d[i]], 1);
    csr[p] = s[i];
  }
}

// ---------------- layer2_fc repack: w2p[k4*256 + lane*4 + i] = fc[lane][k4*4+i]
__global__ void k_w2p(const float* __restrict__ fc, float* __restrict__ w2p){
  int t = blockIdx.x*256 + threadIdx.x;
  if (t < 64*256){
    int k4 = t >> 8, r = t & 255, l = r >> 2, i = r & 3;
    w2p[t] = fc[l*256 + k4*4 + i];
  }
}

// ---------------- fused layer1 GAT + ELU + 256->64 matvec + layer2 scores
__global__ __launch_bounds__(256) void k_gat1(
    const uint2* __restrict__ zb, const float* __restrict__ s1src, const float* __restrict__ s1dst,
    const int* __restrict__ rowptr, const int* __restrict__ csr,
    const float* __restrict__ w2p, const float* __restrict__ a2w,
    ushort_t* __restrict__ z2b, float* __restrict__ s2src, float* __restrict__ s2dst, int N)
{
  __shared__ __align__(16) float hnei[4][256];
  __shared__ int   sbuf[4][CAP];
  __shared__ __align__(16) float4 ebuf[4][CAP];
  const int wave = threadIdx.x >> 6, lane = threadIdx.x & 63;
  const int dst = blockIdx.x*4 + wave;
  const bool act = dst < N;
  if (act){
    const int beg = rowptr[dst];
    const int deg = rowptr[dst+1] - beg;
    const float4 sd = *(const float4*)&s1dst[dst*4];
    // pass1: e per edge, running max
    float m0=-INFINITY, m1=-INFINITY, m2=-INFINITY, m3=-INFINITY;
    for (int j = lane; j < deg; j += 64){
      int s = csr[beg+j];
      float4 sv = *(const float4*)&s1src[s*4];
      float4 e;
      e.x = lrelu(sv.x+sd.x); e.y = lrelu(sv.y+sd.y);
      e.z = lrelu(sv.z+sd.z); e.w = lrelu(sv.w+sd.w);
      if (j < CAP){ sbuf[wave][j] = s; ebuf[wave][j] = e; }
      m0 = fmaxf(m0,e.x); m1 = fmaxf(m1,e.y); m2 = fmaxf(m2,e.z); m3 = fmaxf(m3,e.w);
    }
    m0 = wred_max(m0); m1 = wred_max(m1); m2 = wred_max(m2); m3 = wred_max(m3);
    // pass2: exp + denominators; ebuf <- exp(e-m)
    float t0=0.f,t1=0.f,t2=0.f,t3=0.f;
    for (int j = lane; j < deg; j += 64){
      float4 e;
      if (j < CAP) e = ebuf[wave][j];
      else {
        int s = csr[beg+j];
        float4 sv = *(const float4*)&s1src[s*4];
        e.x = lrelu(sv.x+sd.x); e.y = lrelu(sv.y+sd.y);
        e.z = lrelu(sv.z+sd.z); e.w = lrelu(sv.w+sd.w);
      }
      float4 a;
      a.x = __expf(e.x-m0); a.y = __expf(e.y-m1);
      a.z = __expf(e.z-m2); a.w = __expf(e.w-m3);
      t0 += a.x; t1 += a.y; t2 += a.z; t3 += a.w;
      if (j < CAP) ebuf[wave][j] = a;
    }
    const float i0 = 1.f/wred_sum(t0), i1 = 1.f/wred_sum(t1);
    const float i2 = 1.f/wred_sum(t2), i3 = 1.f/wred_sum(t3);
    // pass2b: fold 1/denom -> alphas in LDS
    const int capd = deg < CAP ? deg : CAP;
    for (int j = lane; j < capd; j += 64){
      float4 a = ebuf[wave][j];
      a.x *= i0; a.y *= i1; a.z *= i2; a.w *= i3;
      ebuf[wave][j] = a;
    }
    // pass3: aggregation, lane = dim, one dwordx2 per edge
    float a0=0.f,a1=0.f,a2v=0.f,a3=0.f;
#pragma unroll 4
    for (int j = 0; j < deg; j++){
      int s; float4 al;
      if (j < CAP){ s = sbuf[wave][j]; al = ebuf[wave][j]; }
      else {
        s = csr[beg+j];
        float4 sv = *(const float4*)&s1src[s*4];
        al.x = __expf(lrelu(sv.x+sd.x)-m0)*i0; al.y = __expf(lrelu(sv.y+sd.y)-m1)*i1;
        al.z = __expf(lrelu(sv.z+sd.z)-m2)*i2; al.w = __expf(lrelu(sv.w+sd.w)-m3)*i3;
      }
      uint2 u = zb[(size_t)s*64 + lane];
      a0  += al.x * b2f_lo(u.x);
      a1  += al.y * b2f_hi(u.x);
      a2v += al.z * b2f_lo(u.y);
      a3  += al.w * b2f_hi(u.y);
    }
    hnei[wave][lane]     = a0  > 0.f ? a0  : expm1f(a0);
    hnei[wave][64+lane]  = a1  > 0.f ? a1  : expm1f(a1);
    hnei[wave][128+lane] = a2v > 0.f ? a2v : expm1f(a2v);
    hnei[wave][192+lane] = a3  > 0.f ? a3  : expm1f(a3);
  }
  __syncthreads();
  if (act){
    float zv = 0.f;
#pragma unroll 8
    for (int k4 = 0; k4 < 64; k4++){
      float4 hv = *(const float4*)&hnei[wave][k4*4];
      float4 wv = *(const float4*)&w2p[k4*256 + lane*4];
      zv += hv.x*wv.x + hv.y*wv.y + hv.z*wv.z + hv.w*wv.w;
    }
    z2b[(size_t)dst*64 + lane] = f2b(zv);
    float ss  = wred_sum(zv * a2w[lane]);
    float sd2 = wred_sum(zv * a2w[64+lane]);
    if (lane == 0){ s2src[dst] = ss; s2dst[dst] = sd2; }
  }
}

// ---------------- layer2 GAT, reduced straight to the global sum
__global__ __launch_bounds__(256) void k_gat2(
    const ushort_t* __restrict__ z2b, const float* __restrict__ s2src, const float* __restrict__ s2dst,
    const int* __restrict__ rowptr, const int* __restrict__ csr,
    float* __restrict__ accOut, int N)
{
  __shared__ int   sbuf[4][CAP];
  __shared__ float ebuf[4][CAP];
  __shared__ float red[4][64];
  const int wave = threadIdx.x >> 6, lane = threadIdx.x & 63;
  float g = 0.f;
  const int stride = gridDim.x * 4;
  for (int dst = blockIdx.x*4 + wave; dst < N; dst += stride){
    int beg = rowptr[dst], deg = rowptr[dst+1] - beg;
    float sd = s2dst[dst];
    float mx = -INFINITY;
    for (int j = lane; j < deg; j += 64){
      int s = csr[beg+j];
      float e = lrelu(s2src[s] + sd);
      if (j < CAP){ sbuf[wave][j] = s; ebuf[wave][j] = e; }
      mx = fmaxf(mx, e);
    }
    float m = wred_max(mx);
    float ts = 0.f;
    for (int j = lane; j < deg; j += 64){
      float e = (j < CAP) ? ebuf[wave][j] : lrelu(s2src[csr[beg+j]] + sd);
      float a = __expf(e - m);
      ts += a;
      if (j < CAP) ebuf[wave][j] = a;
    }
    float inv = 1.f/wred_sum(ts);
    int capd = deg < CAP ? deg : CAP;
    for (int j = lane; j < capd; j += 64) ebuf[wave][j] *= inv;
#pragma unroll 4
    for (int j = 0; j < deg; j++){
      int s; float al;
      if (j < CAP){ s = sbuf[wave][j]; al = ebuf[wave][j]; }
      else { s = csr[beg+j]; al = __expf(lrelu(s2src[s] + sd) - m)*inv; }
      g += al * __uint_as_float(((uint_t)z2b[(size_t)s*64 + lane]) << 16);
    }
  }
  red[wave][lane] = g;
  __syncthreads();
  if (wave == 0)
    atomicAdd(&accOut[lane], red[0][lane]+red[1][lane]+red[2][lane]+red[3][lane]);
}

// ---------------- fractal: acc[s][k] = sum_n h[fcm[n,s]][k]   (exact f32)
__global__ __launch_bounds__(256) void k_frac(const float* __restrict__ h,
    const int* __restrict__ fcm, float* __restrict__ accFrac, int N)
{
  __shared__ float red[4][6][64];
  const int wave = threadIdx.x >> 6, lane = threadIdx.x & 63;
  float a[6] = {0.f,0.f,0.f,0.f,0.f,0.f};
  const int stride = gridDim.x * 4;
  for (int n = blockIdx.x*4 + wave; n < N; n += stride){
    int i0 = fcm[n*3], i1 = fcm[n*3+1], i2 = fcm[n*3+2];
    a[0] += h[(size_t)i0*128 + lane]; a[1] += h[(size_t)i0*128 + 64 + lane];
    a[2] += h[(size_t)i1*128 + lane]; a[3] += h[(size_t)i1*128 + 64 + lane];
    a[4] += h[(size_t)i2*128 + lane]; a[5] += h[(size_t)i2*128 + 64 + lane];
  }
#pragma unroll
  for (int q = 0; q < 6; q++) red[wave][q][lane] = a[q];
  __syncthreads();
  if (wave == 0){
#pragma unroll
    for (int q = 0; q < 6; q++){
      float v = red[0][q][lane]+red[1][q][lane]+red[2][q][lane]+red[3][q][lane];
      atomicAdd(&accFrac[(q>>1)*128 + (q&1)*64 + lane], v);
    }
  }
}

// ---------------- finalize
__global__ __launch_bounds__(256) void k_finalize(const float* __restrict__ acc,
    const float* __restrict__ frw, const float* __restrict__ frf,
    const float* __restrict__ fc2, float* __restrict__ out, float invN)
{
  __shared__ float g[384], mm[192], hfrac[64], nei[64];
  int t = threadIdx.x;
  for (int i = t; i < 384; i += 256) g[i] = acc[64 + i] * invN;
  if (t < 64) nei[t] = acc[t] * invN;
  __syncthreads();
  for (int i = t; i < 192; i += 256){
    int s = i >> 6, d = i & 63;
    const float* w = frw + (size_t)(s*64 + d)*128;
    const float* gs = g + s*128;
    float sum = 0.f;
    for (int k = 0; k < 128; k++) sum += gs[k]*w[k];
    mm[i] = sum;
  }
  __syncthreads();
  if (t < 64){
    float s = 0.f;
    for (int k = 0; k < 192; k++) s += mm[k]*frf[t*192 + k];
    hfrac[t] = s;
  }
  __syncthreads();
  if (t < 64){
    float o = 0.f;
    for (int k = 0; k < 64; k++)
      o += fc2[t*128 + k]*nei[k] + fc2[t*128 + 64 + k]*hfrac[k];
    out[t] = o;
  }
}

extern "C" void kernel_launch(void* const* d_in, const int* in_sizes, int n_in,
                              void* d_out, int out_size, void* d_ws, size_t ws_size,
                              hipStream_t stream)
{
  const float* h    = (const float*)d_in[0];
  const int*   srcI = (const int*)  d_in[1];
  const int*   dstI = (const int*)  d_in[2];
  const int*   fcm  = (const int*)  d_in[3];
  const float* l1fc = (const float*)d_in[4];
  const float* l1at = (const float*)d_in[5];
  const float* l2fc = (const float*)d_in[6];
  const float* l2at = (const float*)d_in[7];
  const float* frw  = (const float*)d_in[8];
  const float* frf  = (const float*)d_in[9];
  const float* fc2  = (const float*)d_in[10];
  float* out = (float*)d_out;
  (void)n_in; (void)out_size; (void)ws_size;

  const int N = in_sizes[0] / 128;
  const int E = in_sizes[1];
  const int B = (N + 256) / 256;     // ceil((N+1)/256) so rowptr[N] is covered
  const int PAD = B * 256;

  char* w = (char*)d_ws;
  size_t off = 0;
  auto alloc = [&](size_t bytes) -> char* {
    char* p = w + off; off = (off + bytes + 255) & ~(size_t)255; return p;
  };
  uint2*    zb   = (uint2*)   alloc((size_t)N*64*8);   // 51.2 MB packed bf16 z
  ushort_t* z2b  = (ushort_t*)alloc((size_t)N*64*2);   // 12.8 MB bf16 z2
  float* s1s  = (float*)alloc((size_t)N*4*4);
  float* s1d  = (float*)alloc((size_t)N*4*4);
  float* s2s  = (float*)alloc((size_t)N*4);
  float* s2d  = (float*)alloc((size_t)N*4);
  int*   deg    = (int*)alloc((size_t)PAD*4);
  int*   rowptr = (int*)alloc((size_t)PAD*4);
  int*   cursor = (int*)alloc((size_t)PAD*4);
  int*   part   = (int*)alloc(512*4);
  int*   csr    = (int*)alloc((size_t)E*4);
  float* w2p    = (float*)alloc(16384*4);
  float* acc    = (float*)alloc(448*4);   // [0:64) nei2-sum, [64:448) frac-sum

  hipMemsetAsync(deg, 0, (size_t)PAD*4, stream);
  hipMemsetAsync(acc, 0, 448*4, stream);

  hipLaunchKernelGGL(k_w2p,     dim3(64),            dim3(256), 0, stream, l2fc, w2p);
  hipLaunchKernelGGL(k_hist,    dim3((E+255)/256),   dim3(256), 0, stream, dstI, deg, E);
  hipLaunchKernelGGL(k_scan1,   dim3(B),             dim3(256), 0, stream, deg, part);
  hipLaunchKernelGGL(k_scan2,   dim3(1),             dim3(512), 0, stream, part, B);
  hipLaunchKernelGGL(k_scan3,   dim3(B),             dim3(256), 0, stream, deg, part, rowptr, cursor);
  hipLaunchKernelGGL(k_scatter, dim3((E+255)/256),   dim3(256), 0, stream, srcI, dstI, cursor, csr, E);
  hipLaunchKernelGGL(k_gemm1f,  dim3((N+63)/64),     dim3(256), 0, stream,
                     h, l1fc, l1at, zb, s1s, s1d, N);
  hipLaunchKernelGGL(k_gat1,    dim3((N+3)/4),       dim3(256), 0, stream,
                     zb, s1s, s1d, rowptr, csr, w2p, l2at, z2b, s2s, s2d, N);
  hipLaunchKernelGGL(k_gat2,    dim3(1024),          dim3(256), 0, stream,
                     z2b, s2s, s2d, rowptr, csr, acc, N);
  hipLaunchKernelGGL(k_frac,    dim3(1024),          dim3(256), 0, stream, h, fcm, acc + 64, N);
  hipLaunchKernelGGL(k_finalize,dim3(1),             dim3(256), 0, stream,
                     acc, frw, frf, fc2, out, 1.0f/(float)N);
}

// Round 3
// 868.886 us; speedup vs baseline: 1.0725x; 1.0654x over previous
//
#include <hip/hip_runtime.h>
#include <math.h>

// GAT pipeline. bf16-packed z/z2; no-max softmax (scores bounded ~|8|, exp safe
// in f32, softmax is shift-invariant); multi-edge gather parallelism in the
// aggregation passes (2 edges/iter in gat1, 4 edges/iter in gat2).

#define CAP 128   // per-wave LDS edge cache; deg>CAP falls back to recompute

typedef unsigned int  uint_t;
typedef unsigned short ushort_t;

__device__ __forceinline__ float wred_sum(float v){
#pragma unroll
  for (int o = 1; o < 64; o <<= 1) v += __shfl_xor(v, o, 64);
  return v;
}
__device__ __forceinline__ float lrelu(float x){ return x >= 0.f ? x : 0.01f*x; }
__device__ __forceinline__ ushort_t f2b(float f){
  uint_t u = __float_as_uint(f);
  u = (u + 0x7FFFu + ((u >> 16) & 1u)) >> 16;   // RNE
  return (ushort_t)u;
}
__device__ __forceinline__ float b2f_lo(uint_t w){ return __uint_as_float(w << 16); }
__device__ __forceinline__ float b2f_hi(uint_t w){ return __uint_as_float(w & 0xFFFF0000u); }

// ---------------- GEMM1 fused: zb[N][64] uint2 (4 heads bf16 per dim) + layer1 scores
__global__ __launch_bounds__(256) void k_gemm1f(const float* __restrict__ h,
    const float* __restrict__ W, const float* __restrict__ a1,
    uint2* __restrict__ zb, float* __restrict__ s1s, float* __restrict__ s1d, int N)
{
  __shared__ __align__(16) float As[16][72];    // [k][row]
  __shared__ __align__(16) float Bs[16][260];   // [k][col]
  __shared__ float a1s[512];
  const int t = threadIdx.x;
  const int tx = t & 15, ty = t >> 4;
  const int m0 = blockIdx.x * 64;
  a1s[t] = a1[t];
  a1s[t + 256] = a1[t + 256];
  const int arow = t >> 2, alk = (t & 3) * 4;
  float acc[4][4][4] = {};
  for (int kk = 0; kk < 128; kk += 16){
    float4 av = make_float4(0.f,0.f,0.f,0.f);
    if (m0 + arow < N) av = *(const float4*)&h[(size_t)(m0+arow)*128 + kk + alk];
    As[alk+0][arow]=av.x; As[alk+1][arow]=av.y; As[alk+2][arow]=av.z; As[alk+3][arow]=av.w;
#pragma unroll
    for (int q = 0; q < 4; q++){
      float4 bv = *(const float4*)&W[(size_t)t*128 + kk + q*4];
      Bs[q*4+0][t]=bv.x; Bs[q*4+1][t]=bv.y; Bs[q*4+2][t]=bv.z; Bs[q*4+3][t]=bv.w;
    }
    __syncthreads();
#pragma unroll
    for (int k = 0; k < 16; k++){
      float4 a4 = *(const float4*)&As[k][ty*4];
      float ar[4] = {a4.x, a4.y, a4.z, a4.w};
#pragma unroll
      for (int hh = 0; hh < 4; hh++){
        float4 b4 = *(const float4*)&Bs[k][hh*64 + tx*4];
        float br[4] = {b4.x, b4.y, b4.z, b4.w};
#pragma unroll
        for (int i = 0; i < 4; i++)
#pragma unroll
          for (int j = 0; j < 4; j++) acc[i][hh][j] += ar[i]*br[j];
      }
    }
    __syncthreads();
  }
#pragma unroll
  for (int i = 0; i < 4; i++){
    const int row = m0 + ty*4 + i;
#pragma unroll
    for (int hh = 0; hh < 4; hh++){
      float ps = 0.f, pd = 0.f;
#pragma unroll
      for (int j = 0; j < 4; j++){
        float v = acc[i][hh][j];
        ps += v * a1s[hh*128 + tx*4 + j];
        pd += v * a1s[hh*128 + 64 + tx*4 + j];
      }
#pragma unroll
      for (int o = 1; o < 16; o <<= 1){
        ps += __shfl_xor(ps, o, 64);
        pd += __shfl_xor(pd, o, 64);
      }
      if (tx == 0 && row < N){ s1s[row*4+hh] = ps; s1d[row*4+hh] = pd; }
    }
  }
#pragma unroll
  for (int i = 0; i < 4; i++){
    const int row = m0 + ty*4 + i;
    if (row < N){
#pragma unroll
      for (int j = 0; j < 4; j++){
        uint_t w0 = (uint_t)f2b(acc[i][0][j]) | ((uint_t)f2b(acc[i][1][j]) << 16);
        uint_t w1 = (uint_t)f2b(acc[i][2][j]) | ((uint_t)f2b(acc[i][3][j]) << 16);
        zb[(size_t)row*64 + tx*4 + j] = make_uint2(w0, w1);
      }
    }
  }
}

// ---------------- CSR build
__global__ void k_hist(const int* __restrict__ d, int* __restrict__ deg, int E){
  int i = blockIdx.x*256 + threadIdx.x;
  if (i < E) atomicAdd(&deg[d[i]], 1);
}
__global__ __launch_bounds__(256) void k_scan1(const int* __restrict__ deg, int* __restrict__ part){
  __shared__ int tmp[256];
  int t = threadIdx.x;
  tmp[t] = deg[blockIdx.x*256 + t];
  __syncthreads();
  for (int off = 128; off > 0; off >>= 1){
    if (t < off) tmp[t] += tmp[t+off];
    __syncthreads();
  }
  if (t == 0) part[blockIdx.x] = tmp[0];
}
__global__ __launch_bounds__(512) void k_scan2(int* __restrict__ part, int B){
  __shared__ int tmp[512];
  int t = threadIdx.x;
  int v = (t < B) ? part[t] : 0;
  tmp[t] = v; __syncthreads();
  for (int off = 1; off < 512; off <<= 1){
    int x = (t >= off) ? tmp[t-off] : 0;
    __syncthreads();
    tmp[t] += x;
    __syncthreads();
  }
  if (t < B) part[t] = tmp[t] - v;   // exclusive
}
__global__ __launch_bounds__(256) void k_scan3(const int* __restrict__ deg, const int* __restrict__ part,
    int* __restrict__ rowptr, int* __restrict__ cursor){
  __shared__ int tmp[256];
  int t = threadIdx.x, i = blockIdx.x*256 + t;
  int v = deg[i];
  tmp[t] = v; __syncthreads();
  for (int off = 1; off < 256; off <<= 1){
    int x = (t >= off) ? tmp[t-off] : 0;
    __syncthreads();
    tmp[t] += x;
    __syncthreads();
  }
  int excl = tmp[t] - v + part[blockIdx.x];
  rowptr[i] = excl; cursor[i] = excl;
}
__global__ void k_scatter(const int* __restrict__ s, const int* __restrict__ d,
    int* __restrict__ cursor, int* __restrict__ csr, int E){
  int i = blockIdx.x*256 + threadIdx.x;
  if (i < E){
    int p = atomicAdd(&cursor[d[i]], 1);
    csr[p] = s[i];
  }
}

// ---------------- layer2_fc repack: w2p[k4*256 + lane*4 + i] = fc[lane][k4*4+i]
__global__ void k_w2p(const float* __restrict__ fc, float* __restrict__ w2p){
  int t = blockIdx.x*256 + threadIdx.x;
  if (t < 64*256){
    int k4 = t >> 8, r = t & 255, l = r >> 2, i = r & 3;
    w2p[t] = fc[l*256 + k4*4 + i];
  }
}

// ---------------- fused layer1 GAT + ELU + 256->64 matvec + layer2 scores
__global__ __launch_bounds__(256) void k_gat1(
    const uint2* __restrict__ zb, const float* __restrict__ s1src, const float* __restrict__ s1dst,
    const int* __restrict__ rowptr, const int* __restrict__ csr,
    const float* __restrict__ w2p, const float* __restrict__ a2w,
    ushort_t* __restrict__ z2b, float* __restrict__ s2src, float* __restrict__ s2dst, int N)
{
  __shared__ __align__(16) float hnei[4][256];
  __shared__ int   sbuf[4][CAP];
  __shared__ __align__(16) float4 ebuf[4][CAP];
  const int wave = threadIdx.x >> 6, lane = threadIdx.x & 63;
  const int dst = blockIdx.x*4 + wave;
  const bool act = dst < N;
  if (act){
    const int beg = rowptr[dst];
    const int deg = rowptr[dst+1] - beg;
    const float4 sd = *(const float4*)&s1dst[dst*4];
    // pass A: exp(e) per edge (no max shift: |e|<=~8, safe), denominators
    float t0=0.f,t1=0.f,t2=0.f,t3=0.f;
    for (int j = lane; j < deg; j += 64){
      int s = csr[beg+j];
      float4 sv = *(const float4*)&s1src[s*4];
      float4 a;
      a.x = __expf(lrelu(sv.x+sd.x)); a.y = __expf(lrelu(sv.y+sd.y));
      a.z = __expf(lrelu(sv.z+sd.z)); a.w = __expf(lrelu(sv.w+sd.w));
      if (j < CAP){ sbuf[wave][j] = s; ebuf[wave][j] = a; }
      t0 += a.x; t1 += a.y; t2 += a.z; t3 += a.w;
    }
    const float i0 = 1.f/wred_sum(t0), i1 = 1.f/wred_sum(t1);
    const float i2 = 1.f/wred_sum(t2), i3 = 1.f/wred_sum(t3);
    // pass B: aggregation, 2 edges/iteration (32 lanes x uint4 = 512B row each)
    const int eh = lane >> 5, li = lane & 31;
    float acc[2][4] = {};
#pragma unroll 2
    for (int jj = 0; jj < deg; jj += 2){
      const int j = jj + eh;
      const bool v = j < deg;
      const int jc = v ? j : jj;
      int s; float4 al;
      if (jc < CAP){ s = sbuf[wave][jc]; al = ebuf[wave][jc]; }
      else {
        s = csr[beg+jc];
        float4 sv = *(const float4*)&s1src[s*4];
        al.x = __expf(lrelu(sv.x+sd.x)); al.y = __expf(lrelu(sv.y+sd.y));
        al.z = __expf(lrelu(sv.z+sd.z)); al.w = __expf(lrelu(sv.w+sd.w));
      }
      if (!v){ al.x = 0.f; al.y = 0.f; al.z = 0.f; al.w = 0.f; }
      uint4 u = *((const uint4*)(zb + (size_t)s*64) + li);  // dims 2li, 2li+1
      acc[0][0] += al.x * b2f_lo(u.x);
      acc[0][1] += al.y * b2f_hi(u.x);
      acc[0][2] += al.z * b2f_lo(u.y);
      acc[0][3] += al.w * b2f_hi(u.y);
      acc[1][0] += al.x * b2f_lo(u.z);
      acc[1][1] += al.y * b2f_hi(u.z);
      acc[1][2] += al.z * b2f_lo(u.w);
      acc[1][3] += al.w * b2f_hi(u.w);
    }
    // combine parity halves
#pragma unroll
    for (int k = 0; k < 2; k++)
#pragma unroll
      for (int hh = 0; hh < 4; hh++) acc[k][hh] += __shfl_xor(acc[k][hh], 32, 64);
    if (eh == 0){
      const float inv[4] = {i0, i1, i2, i3};
#pragma unroll
      for (int hh = 0; hh < 4; hh++){
        float v0 = acc[0][hh]*inv[hh]; v0 = v0 > 0.f ? v0 : expm1f(v0);
        float v1 = acc[1][hh]*inv[hh]; v1 = v1 > 0.f ? v1 : expm1f(v1);
        hnei[wave][hh*64 + 2*li]   = v0;
        hnei[wave][hh*64 + 2*li+1] = v1;
      }
    }
  }
  __syncthreads();
  if (act){
    float zv = 0.f;
#pragma unroll 8
    for (int k4 = 0; k4 < 64; k4++){
      float4 hv = *(const float4*)&hnei[wave][k4*4];
      float4 wv = *(const float4*)&w2p[k4*256 + lane*4];
      zv += hv.x*wv.x + hv.y*wv.y + hv.z*wv.z + hv.w*wv.w;
    }
    z2b[(size_t)dst*64 + lane] = f2b(zv);
    float ss  = wred_sum(zv * a2w[lane]);
    float sd2 = wred_sum(zv * a2w[64+lane]);
    if (lane == 0){ s2src[dst] = ss; s2dst[dst] = sd2; }
  }
}

// ---------------- layer2 GAT, reduced straight to the global sum
__global__ __launch_bounds__(256) void k_gat2(
    const ushort_t* __restrict__ z2b, const float* __restrict__ s2src, const float* __restrict__ s2dst,
    const int* __restrict__ rowptr, const int* __restrict__ csr,
    float* __restrict__ accOut, int N)
{
  __shared__ int   sbuf[4][CAP];
  __shared__ float ebuf[4][CAP];
  __shared__ __align__(16) float red[4][64];
  const int wave = threadIdx.x >> 6, lane = threadIdx.x & 63;
  const int g4 = lane >> 4, li = lane & 15;
  float g0=0.f, g1=0.f, g2=0.f, g3=0.f;
  const int stride = gridDim.x * 4;
  for (int dst = blockIdx.x*4 + wave; dst < N; dst += stride){
    const int beg = rowptr[dst], deg = rowptr[dst+1] - beg;
    const float sd = s2dst[dst];
    // pass A: exp + denom
    float ts = 0.f;
    for (int j = lane; j < deg; j += 64){
      int s = csr[beg+j];
      float a = __expf(lrelu(s2src[s] + sd));
      if (j < CAP){ sbuf[wave][j] = s; ebuf[wave][j] = a; }
      ts += a;
    }
    const float inv = 1.f/wred_sum(ts);
    // pass B: 4 edges/iteration (16 lanes x uint2 = 128B row each)
    float c0=0.f, c1=0.f, c2=0.f, c3=0.f;
#pragma unroll 2
    for (int jj = 0; jj < deg; jj += 4){
      const int j = jj + g4;
      const bool v = j < deg;
      const int jc = v ? j : jj;
      int s; float al;
      if (jc < CAP){ s = sbuf[wave][jc]; al = ebuf[wave][jc]; }
      else { s = csr[beg+jc]; al = __expf(lrelu(s2src[s] + sd)); }
      if (!v) al = 0.f;
      uint2 u = *((const uint2*)(z2b + (size_t)s*64) + li);  // dims 4li..4li+3
      c0 += al * b2f_lo(u.x);
      c1 += al * b2f_hi(u.x);
      c2 += al * b2f_lo(u.y);
      c3 += al * b2f_hi(u.y);
    }
    c0 += __shfl_xor(c0,16,64); c0 += __shfl_xor(c0,32,64);
    c1 += __shfl_xor(c1,16,64); c1 += __shfl_xor(c1,32,64);
    c2 += __shfl_xor(c2,16,64); c2 += __shfl_xor(c2,32,64);
    c3 += __shfl_xor(c3,16,64); c3 += __shfl_xor(c3,32,64);
    g0 += inv*c0; g1 += inv*c1; g2 += inv*c2; g3 += inv*c3;
  }
  if (g4 == 0) *(float4*)&red[wave][li*4] = make_float4(g0,g1,g2,g3);
  __syncthreads();
  if (wave == 0)
    atomicAdd(&accOut[lane], red[0][lane]+red[1][lane]+red[2][lane]+red[3][lane]);
}

// ---------------- fractal: acc[s][k] = sum_n h[fcm[n,s]][k]   (exact f32)
__global__ __launch_bounds__(256) void k_frac(const float* __restrict__ h,
    const int* __restrict__ fcm, float* __restrict__ accFrac, int N)
{
  __shared__ float red[4][6][64];
  const int wave = threadIdx.x >> 6, lane = threadIdx.x & 63;
  float a[6] = {0.f,0.f,0.f,0.f,0.f,0.f};
  const int stride = gridDim.x * 4;
  for (int n = blockIdx.x*4 + wave; n < N; n += stride){
    int i0 = fcm[n*3], i1 = fcm[n*3+1], i2 = fcm[n*3+2];
    a[0] += h[(size_t)i0*128 + lane]; a[1] += h[(size_t)i0*128 + 64 + lane];
    a[2] += h[(size_t)i1*128 + lane]; a[3] += h[(size_t)i1*128 + 64 + lane];
    a[4] += h[(size_t)i2*128 + lane]; a[5] += h[(size_t)i2*128 + 64 + lane];
  }
#pragma unroll
  for (int q = 0; q < 6; q++) red[wave][q][lane] = a[q];
  __syncthreads();
  if (wave == 0){
#pragma unroll
    for (int q = 0; q < 6; q++){
      float v = red[0][q][lane]+red[1][q][lane]+red[2][q][lane]+red[3][q][lane];
      atomicAdd(&accFrac[(q>>1)*128 + (q&1)*64 + lane], v);
    }
  }
}

// ---------------- finalize
__global__ __launch_bounds__(256) void k_finalize(const float* __restrict__ acc,
    const float* __restrict__ frw, const float* __restrict__ frf,
    const float* __restrict__ fc2, float* __restrict__ out, float invN)
{
  __shared__ float g[384], mm[192], hfrac[64], nei[64];
  int t = threadIdx.x;
  for (int i = t; i < 384; i += 256) g[i] = acc[64 + i] * invN;
  if (t < 64) nei[t] = acc[t] * invN;
  __syncthreads();
  for (int i = t; i < 192; i += 256){
    int s = i >> 6, d = i & 63;
    const float* w = frw + (size_t)(s*64 + d)*128;
    const float* gs = g + s*128;
    float sum = 0.f;
    for (int k = 0; k < 128; k++) sum += gs[k]*w[k];
    mm[i] = sum;
  }
  __syncthreads();
  if (t < 64){
    float s = 0.f;
    for (int k = 0; k < 192; k++) s += mm[k]*frf[t*192 + k];
    hfrac[t] = s;
  }
  __syncthreads();
  if (t < 64){
    float o = 0.f;
    for (int k = 0; k < 64; k++)
      o += fc2[t*128 + k]*nei[k] + fc2[t*128 + 64 + k]*hfrac[k];
    out[t] = o;
  }
}

extern "C" void kernel_launch(void* const* d_in, const int* in_sizes, int n_in,
                              void* d_out, int out_size, void* d_ws, size_t ws_size,
                              hipStream_t stream)
{
  const float* h    = (const float*)d_in[0];
  const int*   srcI = (const int*)  d_in[1];
  const int*   dstI = (const int*)  d_in[2];
  const int*   fcm  = (const int*)  d_in[3];
  const float* l1fc = (const float*)d_in[4];
  const float* l1at = (const float*)d_in[5];
  const float* l2fc = (const float*)d_in[6];
  const float* l2at = (const float*)d_in[7];
  const float* frw  = (const float*)d_in[8];
  const float* frf  = (const float*)d_in[9];
  const float* fc2  = (const float*)d_in[10];
  float* out = (float*)d_out;
  (void)n_in; (void)out_size; (void)ws_size;

  const int N = in_sizes[0] / 128;
  const int E = in_sizes[1];
  const int B = (N + 256) / 256;     // ceil((N+1)/256) so rowptr[N] is covered
  const int PAD = B * 256;

  char* w = (char*)d_ws;
  size_t off = 0;
  auto alloc = [&](size_t bytes) -> char* {
    char* p = w + off; off = (off + bytes + 255) & ~(size_t)255; return p;
  };
  uint2*    zb   = (uint2*)   alloc((size_t)N*64*8);   // 51.2 MB packed bf16 z
  ushort_t* z2b  = (ushort_t*)alloc((size_t)N*64*2);   // 12.8 MB bf16 z2
  float* s1s  = (float*)alloc((size_t)N*4*4);
  float* s1d  = (float*)alloc((size_t)N*4*4);
  float* s2s  = (float*)alloc((size_t)N*4);
  float* s2d  = (float*)alloc((size_t)N*4);
  int*   deg    = (int*)alloc((size_t)PAD*4);
  int*   rowptr = (int*)alloc((size_t)PAD*4);
  int*   cursor = (int*)alloc((size_t)PAD*4);
  int*   part   = (int*)alloc(512*4);
  int*   csr    = (int*)alloc((size_t)E*4);
  float* w2p    = (float*)alloc(16384*4);
  float* acc    = (float*)alloc(448*4);   // [0:64) nei2-sum, [64:448) frac-sum

  hipMemsetAsync(deg, 0, (size_t)PAD*4, stream);
  hipMemsetAsync(acc, 0, 448*4, stream);

  hipLaunchKernelGGL(k_w2p,     dim3(64),            dim3(256), 0, stream, l2fc, w2p);
  hipLaunchKernelGGL(k_hist,    dim3((E+255)/256),   dim3(256), 0, stream, dstI, deg, E);
  hipLaunchKernelGGL(k_scan1,   dim3(B),             dim3(256), 0, stream, deg, part);
  hipLaunchKernelGGL(k_scan2,   dim3(1),             dim3(512), 0, stream, part, B);
  hipLaunchKernelGGL(k_scan3,   dim3(B),             dim3(256), 0, stream, deg, part, rowptr, cursor);
  hipLaunchKernelGGL(k_scatter, dim3((E+255)/256),   dim3(256), 0, stream, srcI, dstI, cursor, csr, E);
  hipLaunchKernelGGL(k_gemm1f,  dim3((N+63)/64),     dim3(256), 0, stream,
                     h, l1fc, l1at, zb, s1s, s1d, N);
  hipLaunchKernelGGL(k_gat1,    dim3((N+3)/4),       dim3(256), 0, stream,
                     zb, s1s, s1d, rowptr, csr, w2p, l2at, z2b, s2s, s2d, N);
  hipLaunchKernelGGL(k_gat2,    dim3(1024),          dim3(256), 0, stream,
                     z2b, s2s, s2d, rowptr, csr, acc, N);
  hipLaunchKernelGGL(k_frac,    dim3(1024),          dim3(256), 0, stream, h, fcm, acc + 64, N);
  hipLaunchKernelGGL(k_finalize,dim3(1),             dim3(256), 0, stream,
                     acc, frw, frf, fc2, out, 1.0f/(float)N);
}

// Round 4
// 783.303 us; speedup vs baseline: 1.1897x; 1.1093x over previous
//
#include <hip/hip_runtime.h>
#include <math.h>

// GAT pipeline. bf16-packed z/hnei/z2; no-max softmax; gat1 = pure edge
// aggregation (matvec de-fused into an MFMA GEMM2); gat2 reduced to global sum.

#define CAP 128   // per-wave LDS edge cache; deg>CAP falls back to recompute

typedef unsigned int  uint_t;
typedef unsigned short ushort_t;
typedef __attribute__((ext_vector_type(8))) short short8;
typedef __attribute__((ext_vector_type(4))) float floatx4;

__device__ __forceinline__ float wred_sum(float v){
#pragma unroll
  for (int o = 1; o < 64; o <<= 1) v += __shfl_xor(v, o, 64);
  return v;
}
__device__ __forceinline__ float lrelu(float x){ return x >= 0.f ? x : 0.01f*x; }
__device__ __forceinline__ ushort_t f2b(float f){
  uint_t u = __float_as_uint(f);
  u = (u + 0x7FFFu + ((u >> 16) & 1u)) >> 16;   // RNE
  return (ushort_t)u;
}
__device__ __forceinline__ float b2f_lo(uint_t w){ return __uint_as_float(w << 16); }
__device__ __forceinline__ float b2f_hi(uint_t w){ return __uint_as_float(w & 0xFFFF0000u); }

// ---------------- GEMM1 fused: zb[N][64] uint2 (4 heads bf16 per dim) + layer1 scores
__global__ __launch_bounds__(256) void k_gemm1f(const float* __restrict__ h,
    const float* __restrict__ W, const float* __restrict__ a1,
    uint2* __restrict__ zb, float* __restrict__ s1s, float* __restrict__ s1d, int N)
{
  __shared__ __align__(16) float As[16][72];    // [k][row]
  __shared__ __align__(16) float Bs[16][260];   // [k][col]
  __shared__ float a1s[512];
  const int t = threadIdx.x;
  const int tx = t & 15, ty = t >> 4;
  const int m0 = blockIdx.x * 64;
  a1s[t] = a1[t];
  a1s[t + 256] = a1[t + 256];
  const int arow = t >> 2, alk = (t & 3) * 4;
  float acc[4][4][4] = {};
  for (int kk = 0; kk < 128; kk += 16){
    float4 av = make_float4(0.f,0.f,0.f,0.f);
    if (m0 + arow < N) av = *(const float4*)&h[(size_t)(m0+arow)*128 + kk + alk];
    As[alk+0][arow]=av.x; As[alk+1][arow]=av.y; As[alk+2][arow]=av.z; As[alk+3][arow]=av.w;
#pragma unroll
    for (int q = 0; q < 4; q++){
      float4 bv = *(const float4*)&W[(size_t)t*128 + kk + q*4];
      Bs[q*4+0][t]=bv.x; Bs[q*4+1][t]=bv.y; Bs[q*4+2][t]=bv.z; Bs[q*4+3][t]=bv.w;
    }
    __syncthreads();
#pragma unroll
    for (int k = 0; k < 16; k++){
      float4 a4 = *(const float4*)&As[k][ty*4];
      float ar[4] = {a4.x, a4.y, a4.z, a4.w};
#pragma unroll
      for (int hh = 0; hh < 4; hh++){
        float4 b4 = *(const float4*)&Bs[k][hh*64 + tx*4];
        float br[4] = {b4.x, b4.y, b4.z, b4.w};
#pragma unroll
        for (int i = 0; i < 4; i++)
#pragma unroll
          for (int j = 0; j < 4; j++) acc[i][hh][j] += ar[i]*br[j];
      }
    }
    __syncthreads();
  }
#pragma unroll
  for (int i = 0; i < 4; i++){
    const int row = m0 + ty*4 + i;
#pragma unroll
    for (int hh = 0; hh < 4; hh++){
      float ps = 0.f, pd = 0.f;
#pragma unroll
      for (int j = 0; j < 4; j++){
        float v = acc[i][hh][j];
        ps += v * a1s[hh*128 + tx*4 + j];
        pd += v * a1s[hh*128 + 64 + tx*4 + j];
      }
#pragma unroll
      for (int o = 1; o < 16; o <<= 1){
        ps += __shfl_xor(ps, o, 64);
        pd += __shfl_xor(pd, o, 64);
      }
      if (tx == 0 && row < N){ s1s[row*4+hh] = ps; s1d[row*4+hh] = pd; }
    }
  }
#pragma unroll
  for (int i = 0; i < 4; i++){
    const int row = m0 + ty*4 + i;
    if (row < N){
#pragma unroll
      for (int j = 0; j < 4; j++){
        uint_t w0 = (uint_t)f2b(acc[i][0][j]) | ((uint_t)f2b(acc[i][1][j]) << 16);
        uint_t w1 = (uint_t)f2b(acc[i][2][j]) | ((uint_t)f2b(acc[i][3][j]) << 16);
        zb[(size_t)row*64 + tx*4 + j] = make_uint2(w0, w1);
      }
    }
  }
}

// ---------------- CSR build
__global__ void k_hist(const int* __restrict__ d, int* __restrict__ deg, int E){
  int i = blockIdx.x*256 + threadIdx.x;
  if (i < E) atomicAdd(&deg[d[i]], 1);
}
__global__ __launch_bounds__(256) void k_scan1(const int* __restrict__ deg, int* __restrict__ part){
  __shared__ int tmp[256];
  int t = threadIdx.x;
  tmp[t] = deg[blockIdx.x*256 + t];
  __syncthreads();
  for (int off = 128; off > 0; off >>= 1){
    if (t < off) tmp[t] += tmp[t+off];
    __syncthreads();
  }
  if (t == 0) part[blockIdx.x] = tmp[0];
}
__global__ __launch_bounds__(512) void k_scan2(int* __restrict__ part, int B){
  __shared__ int tmp[512];
  int t = threadIdx.x;
  int v = (t < B) ? part[t] : 0;
  tmp[t] = v; __syncthreads();
  for (int off = 1; off < 512; off <<= 1){
    int x = (t >= off) ? tmp[t-off] : 0;
    __syncthreads();
    tmp[t] += x;
    __syncthreads();
  }
  if (t < B) part[t] = tmp[t] - v;   // exclusive
}
__global__ __launch_bounds__(256) void k_scan3(const int* __restrict__ deg, const int* __restrict__ part,
    int* __restrict__ rowptr, int* __restrict__ cursor){
  __shared__ int tmp[256];
  int t = threadIdx.x, i = blockIdx.x*256 + t;
  int v = deg[i];
  tmp[t] = v; __syncthreads();
  for (int off = 1; off < 256; off <<= 1){
    int x = (t >= off) ? tmp[t-off] : 0;
    __syncthreads();
    tmp[t] += x;
    __syncthreads();
  }
  int excl = tmp[t] - v + part[blockIdx.x];
  rowptr[i] = excl; cursor[i] = excl;
}
__global__ void k_scatter(const int* __restrict__ s, const int* __restrict__ d,
    int* __restrict__ cursor, int* __restrict__ csr, int E){
  int i = blockIdx.x*256 + threadIdx.x;
  if (i < E){
    int p = atomicAdd(&cursor[d[i]], 1);
    csr[p] = s[i];
  }
}

// ---------------- W2 pack into MFMA B-frag order:
// w2bp[((t*8+ks)*64 + lane)*8 + j] = bf16(fc[(t*16 + (lane&15))*256 + ks*32 + (lane>>4)*8 + j])
__global__ void k_w2b(const float* __restrict__ fc, ushort_t* __restrict__ w2bp){
  int idx = blockIdx.x*256 + threadIdx.x;
  if (idx < 16384){
    int j = idx & 7, lane = (idx >> 3) & 63, ks = (idx >> 9) & 7, t = idx >> 12;
    int n = t*16 + (lane & 15), k = ks*32 + (lane >> 4)*8 + j;
    w2bp[idx] = f2b(fc[n*256 + k]);
  }
}

// ---------------- layer1 GAT edge aggregation + ELU -> hneib [N,256] bf16
__global__ __launch_bounds__(256) void k_gat1(
    const uint2* __restrict__ zb, const float* __restrict__ s1src, const float* __restrict__ s1dst,
    const int* __restrict__ rowptr, const int* __restrict__ csr,
    uint_t* __restrict__ hneib, int N)
{
  __shared__ int   sbuf[4][CAP];
  __shared__ __align__(16) float4 ebuf[4][CAP];
  const int wave = threadIdx.x >> 6, lane = threadIdx.x & 63;
  const int dst = blockIdx.x*4 + wave;
  if (dst >= N) return;
  const int beg = rowptr[dst];
  const int deg = rowptr[dst+1] - beg;
  const float4 sd = *(const float4*)&s1dst[dst*4];
  // pass A: exp(e) per edge (no max shift: scores bounded, exp safe), denominators
  float t0=0.f,t1=0.f,t2=0.f,t3=0.f;
  for (int j = lane; j < deg; j += 64){
    int s = csr[beg+j];
    float4 sv = *(const float4*)&s1src[s*4];
    float4 a;
    a.x = __expf(lrelu(sv.x+sd.x)); a.y = __expf(lrelu(sv.y+sd.y));
    a.z = __expf(lrelu(sv.z+sd.z)); a.w = __expf(lrelu(sv.w+sd.w));
    if (j < CAP){ sbuf[wave][j] = s; ebuf[wave][j] = a; }
    t0 += a.x; t1 += a.y; t2 += a.z; t3 += a.w;
  }
  const float i0 = 1.f/wred_sum(t0), i1 = 1.f/wred_sum(t1);
  const float i2 = 1.f/wred_sum(t2), i3 = 1.f/wred_sum(t3);
  // pass B: aggregation, 2 edges/iteration (32 lanes x uint4 = 512B row each)
  const int eh = lane >> 5, li = lane & 31;
  float acc[2][4] = {};
  int jj = 0;
  if (deg <= CAP){
    for (; jj + 2 <= deg; jj += 2){
      const int j = jj + eh;
      int s = sbuf[wave][j]; float4 al = ebuf[wave][j];
      uint4 u = *((const uint4*)(zb + (size_t)s*64) + li);
      acc[0][0] += al.x * b2f_lo(u.x);
      acc[0][1] += al.y * b2f_hi(u.x);
      acc[0][2] += al.z * b2f_lo(u.y);
      acc[0][3] += al.w * b2f_hi(u.y);
      acc[1][0] += al.x * b2f_lo(u.z);
      acc[1][1] += al.y * b2f_hi(u.z);
      acc[1][2] += al.z * b2f_lo(u.w);
      acc[1][3] += al.w * b2f_hi(u.w);
    }
    if (jj < deg && eh == 0){
      int s = sbuf[wave][jj]; float4 al = ebuf[wave][jj];
      uint4 u = *((const uint4*)(zb + (size_t)s*64) + li);
      acc[0][0] += al.x * b2f_lo(u.x);
      acc[0][1] += al.y * b2f_hi(u.x);
      acc[0][2] += al.z * b2f_lo(u.y);
      acc[0][3] += al.w * b2f_hi(u.y);
      acc[1][0] += al.x * b2f_lo(u.z);
      acc[1][1] += al.y * b2f_hi(u.z);
      acc[1][2] += al.z * b2f_lo(u.w);
      acc[1][3] += al.w * b2f_hi(u.w);
    }
  } else {
    for (; jj < deg; jj += 2){
      const int j = jj + eh;
      const bool v = j < deg;
      const int jc = v ? j : jj;
      int s; float4 al;
      if (jc < CAP){ s = sbuf[wave][jc]; al = ebuf[wave][jc]; }
      else {
        s = csr[beg+jc];
        float4 sv = *(const float4*)&s1src[s*4];
        al.x = __expf(lrelu(sv.x+sd.x)); al.y = __expf(lrelu(sv.y+sd.y));
        al.z = __expf(lrelu(sv.z+sd.z)); al.w = __expf(lrelu(sv.w+sd.w));
      }
      if (!v){ al.x = 0.f; al.y = 0.f; al.z = 0.f; al.w = 0.f; }
      uint4 u = *((const uint4*)(zb + (size_t)s*64) + li);
      acc[0][0] += al.x * b2f_lo(u.x);
      acc[0][1] += al.y * b2f_hi(u.x);
      acc[0][2] += al.z * b2f_lo(u.y);
      acc[0][3] += al.w * b2f_hi(u.y);
      acc[1][0] += al.x * b2f_lo(u.z);
      acc[1][1] += al.y * b2f_hi(u.z);
      acc[1][2] += al.z * b2f_lo(u.w);
      acc[1][3] += al.w * b2f_hi(u.w);
    }
  }
  // combine parity halves
#pragma unroll
  for (int k = 0; k < 2; k++)
#pragma unroll
    for (int hh = 0; hh < 4; hh++) acc[k][hh] += __shfl_xor(acc[k][hh], 32, 64);
  if (eh == 0){
    const float inv[4] = {i0, i1, i2, i3};
#pragma unroll
    for (int hh = 0; hh < 4; hh++){
      float v0 = acc[0][hh]*inv[hh]; v0 = v0 > 0.f ? v0 : expm1f(v0);
      float v1 = acc[1][hh]*inv[hh]; v1 = v1 > 0.f ? v1 : expm1f(v1);
      // hnei k-index = hh*64 + dim, dims (2li, 2li+1) -> packed uint idx hh*32+li
      hneib[(size_t)dst*128 + hh*32 + li] = (uint_t)f2b(v0) | ((uint_t)f2b(v1) << 16);
    }
  }
}

// ---------------- GEMM2 (MFMA bf16): z2 = hnei @ W2^T, fused scores + bf16 store
// Each wave: one 16-row strip; 4 N-tiles of 16; K=256 in 8 steps of 32.
__global__ __launch_bounds__(256) void k_gemm2(
    const ushort_t* __restrict__ hneib, const ushort_t* __restrict__ w2bp,
    const float* __restrict__ a2w,
    ushort_t* __restrict__ z2b, float* __restrict__ s2s, float* __restrict__ s2d, int N)
{
  const int wave = threadIdx.x >> 6, lane = threadIdx.x & 63;
  const int quad = lane >> 4, l16 = lane & 15;
  const int strip = blockIdx.x*4 + wave;
  const int nstrips = (N + 15) >> 4;
  if (strip >= nstrips) return;
  const int row0 = strip * 16;
  // strip-invariant score weights
  float a2s[4], a2d[4];
#pragma unroll
  for (int t = 0; t < 4; t++){
    a2s[t] = a2w[t*16 + l16];
    a2d[t] = a2w[64 + t*16 + l16];
  }
  const int ar = (row0 + l16 < N) ? (row0 + l16) : (N - 1);   // clamp (dup rows discarded)
  floatx4 c[4] = {{0.f,0.f,0.f,0.f},{0.f,0.f,0.f,0.f},{0.f,0.f,0.f,0.f},{0.f,0.f,0.f,0.f}};
#pragma unroll
  for (int ks = 0; ks < 8; ks++){
    short8 a = *(const short8*)&hneib[(size_t)ar*256 + ks*32 + quad*8];
#pragma unroll
    for (int t = 0; t < 4; t++){
      short8 b = *(const short8*)&w2bp[(size_t)((t*8 + ks)*64 + lane)*8];
      c[t] = __builtin_amdgcn_mfma_f32_16x16x32_bf16(a, b, c[t], 0, 0, 0);
    }
  }
  // epilogue: C layout col=lane&15, row=quad*4+reg
#pragma unroll
  for (int i = 0; i < 4; i++){
    const int r = row0 + quad*4 + i;
    float ps = 0.f, pd = 0.f;
    if (r < N){
#pragma unroll
      for (int t = 0; t < 4; t++){
        float v = c[t][i];
        z2b[(size_t)r*64 + t*16 + l16] = f2b(v);
        ps += v * a2s[t]; pd += v * a2d[t];
      }
#pragma unroll
      for (int o = 1; o < 16; o <<= 1){
        ps += __shfl_xor(ps, o, 64);
        pd += __shfl_xor(pd, o, 64);
      }
      if (l16 == 0){ s2s[r] = ps; s2d[r] = pd; }
    }
  }
}

// ---------------- layer2 GAT, reduced straight to the global sum
__global__ __launch_bounds__(256) void k_gat2(
    const ushort_t* __restrict__ z2b, const float* __restrict__ s2src, const float* __restrict__ s2dst,
    const int* __restrict__ rowptr, const int* __restrict__ csr,
    float* __restrict__ accOut, int N)
{
  __shared__ int   sbuf[4][CAP];
  __shared__ float ebuf[4][CAP];
  __shared__ __align__(16) float red[4][64];
  const int wave = threadIdx.x >> 6, lane = threadIdx.x & 63;
  const int g4 = lane >> 4, li = lane & 15;
  float g0=0.f, g1=0.f, g2=0.f, g3=0.f;
  const int stride = gridDim.x * 4;
  for (int dst = blockIdx.x*4 + wave; dst < N; dst += stride){
    const int beg = rowptr[dst], deg = rowptr[dst+1] - beg;
    const float sd = s2dst[dst];
    float ts = 0.f;
    for (int j = lane; j < deg; j += 64){
      int s = csr[beg+j];
      float a = __expf(lrelu(s2src[s] + sd));
      if (j < CAP){ sbuf[wave][j] = s; ebuf[wave][j] = a; }
      ts += a;
    }
    const float inv = 1.f/wred_sum(ts);
    float c0=0.f, c1=0.f, c2=0.f, c3=0.f;
    int jj = 0;
    if (deg <= CAP){
      for (; jj + 4 <= deg; jj += 4){
        const int j = jj + g4;
        int s = sbuf[wave][j]; float al = ebuf[wave][j];
        uint2 u = *((const uint2*)(z2b + (size_t)s*64) + li);
        c0 += al * b2f_lo(u.x);
        c1 += al * b2f_hi(u.x);
        c2 += al * b2f_lo(u.y);
        c3 += al * b2f_hi(u.y);
      }
      if (jj < deg && g4 < deg - jj){
        const int j = jj + g4;
        int s = sbuf[wave][j]; float al = ebuf[wave][j];
        uint2 u = *((const uint2*)(z2b + (size_t)s*64) + li);
        c0 += al * b2f_lo(u.x);
        c1 += al * b2f_hi(u.x);
        c2 += al * b2f_lo(u.y);
        c3 += al * b2f_hi(u.y);
      }
    } else {
      for (; jj < deg; jj += 4){
        const int j = jj + g4;
        const bool v = j < deg;
        const int jc = v ? j : jj;
        int s; float al;
        if (jc < CAP){ s = sbuf[wave][jc]; al = ebuf[wave][jc]; }
        else { s = csr[beg+jc]; al = __expf(lrelu(s2src[s] + sd)); }
        if (!v) al = 0.f;
        uint2 u = *((const uint2*)(z2b + (size_t)s*64) + li);
        c0 += al * b2f_lo(u.x);
        c1 += al * b2f_hi(u.x);
        c2 += al * b2f_lo(u.y);
        c3 += al * b2f_hi(u.y);
      }
    }
    c0 += __shfl_xor(c0,16,64); c0 += __shfl_xor(c0,32,64);
    c1 += __shfl_xor(c1,16,64); c1 += __shfl_xor(c1,32,64);
    c2 += __shfl_xor(c2,16,64); c2 += __shfl_xor(c2,32,64);
    c3 += __shfl_xor(c3,16,64); c3 += __shfl_xor(c3,32,64);
    g0 += inv*c0; g1 += inv*c1; g2 += inv*c2; g3 += inv*c3;
  }
  if (g4 == 0) *(float4*)&red[wave][li*4] = make_float4(g0,g1,g2,g3);
  __syncthreads();
  if (wave == 0)
    atomicAdd(&accOut[lane], red[0][lane]+red[1][lane]+red[2][lane]+red[3][lane]);
}

// ---------------- fractal: acc[s][k] = sum_n h[fcm[n,s]][k]   (exact f32)
__global__ __launch_bounds__(256) void k_frac(const float* __restrict__ h,
    const int* __restrict__ fcm, float* __restrict__ accFrac, int N)
{
  __shared__ float red[4][6][64];
  const int wave = threadIdx.x >> 6, lane = threadIdx.x & 63;
  float a[6] = {0.f,0.f,0.f,0.f,0.f,0.f};
  const int stride = gridDim.x * 4;
  for (int n = blockIdx.x*4 + wave; n < N; n += stride){
    int i0 = fcm[n*3], i1 = fcm[n*3+1], i2 = fcm[n*3+2];
    a[0] += h[(size_t)i0*128 + lane]; a[1] += h[(size_t)i0*128 + 64 + lane];
    a[2] += h[(size_t)i1*128 + lane]; a[3] += h[(size_t)i1*128 + 64 + lane];
    a[4] += h[(size_t)i2*128 + lane]; a[5] += h[(size_t)i2*128 + 64 + lane];
  }
#pragma unroll
  for (int q = 0; q < 6; q++) red[wave][q][lane] = a[q];
  __syncthreads();
  if (wave == 0){
#pragma unroll
    for (int q = 0; q < 6; q++){
      float v = red[0][q][lane]+red[1][q][lane]+red[2][q][lane]+red[3][q][lane];
      atomicAdd(&accFrac[(q>>1)*128 + (q&1)*64 + lane], v);
    }
  }
}

// ---------------- finalize
__global__ __launch_bounds__(256) void k_finalize(const float* __restrict__ acc,
    const float* __restrict__ frw, const float* __restrict__ frf,
    const float* __restrict__ fc2, float* __restrict__ out, float invN)
{
  __shared__ float g[384], mm[192], hfrac[64], nei[64];
  int t = threadIdx.x;
  for (int i = t; i < 384; i += 256) g[i] = acc[64 + i] * invN;
  if (t < 64) nei[t] = acc[t] * invN;
  __syncthreads();
  for (int i = t; i < 192; i += 256){
    int s = i >> 6, d = i & 63;
    const float* w = frw + (size_t)(s*64 + d)*128;
    const float* gs = g + s*128;
    float sum = 0.f;
    for (int k = 0; k < 128; k++) sum += gs[k]*w[k];
    mm[i] = sum;
  }
  __syncthreads();
  if (t < 64){
    float s = 0.f;
    for (int k = 0; k < 192; k++) s += mm[k]*frf[t*192 + k];
    hfrac[t] = s;
  }
  __syncthreads();
  if (t < 64){
    float o = 0.f;
    for (int k = 0; k < 64; k++)
      o += fc2[t*128 + k]*nei[k] + fc2[t*128 + 64 + k]*hfrac[k];
    out[t] = o;
  }
}

extern "C" void kernel_launch(void* const* d_in, const int* in_sizes, int n_in,
                              void* d_out, int out_size, void* d_ws, size_t ws_size,
                              hipStream_t stream)
{
  const float* h    = (const float*)d_in[0];
  const int*   srcI = (const int*)  d_in[1];
  const int*   dstI = (const int*)  d_in[2];
  const int*   fcm  = (const int*)  d_in[3];
  const float* l1fc = (const float*)d_in[4];
  const float* l1at = (const float*)d_in[5];
  const float* l2fc = (const float*)d_in[6];
  const float* l2at = (const float*)d_in[7];
  const float* frw  = (const float*)d_in[8];
  const float* frf  = (const float*)d_in[9];
  const float* fc2  = (const float*)d_in[10];
  float* out = (float*)d_out;
  (void)n_in; (void)out_size; (void)ws_size;

  const int N = in_sizes[0] / 128;
  const int E = in_sizes[1];
  const int B = (N + 256) / 256;     // ceil((N+1)/256) so rowptr[N] is covered
  const int PAD = B * 256;

  char* w = (char*)d_ws;
  size_t off = 0;
  auto alloc = [&](size_t bytes) -> char* {
    char* p = w + off; off = (off + bytes + 255) & ~(size_t)255; return p;
  };
  uint2*    zb    = (uint2*)   alloc((size_t)N*64*8);   // 51.2 MB packed bf16 z
  uint_t*   hneib = (uint_t*)  alloc((size_t)N*128*4);  // 51.2 MB packed bf16 hnei [N,256]
  ushort_t* z2b   = (ushort_t*)alloc((size_t)N*64*2);   // 12.8 MB bf16 z2
  float* s1s  = (float*)alloc((size_t)N*4*4);
  float* s1d  = (float*)alloc((size_t)N*4*4);
  float* s2s  = (float*)alloc((size_t)N*4);
  float* s2d  = (float*)alloc((size_t)N*4);
  int*   deg    = (int*)alloc((size_t)PAD*4);
  int*   rowptr = (int*)alloc((size_t)PAD*4);
  int*   cursor = (int*)alloc((size_t)PAD*4);
  int*   part   = (int*)alloc(512*4);
  int*   csr    = (int*)alloc((size_t)E*4);
  ushort_t* w2bp = (ushort_t*)alloc(16384*2);
  float* acc    = (float*)alloc(448*4);   // [0:64) nei2-sum, [64:448) frac-sum

  hipMemsetAsync(deg, 0, (size_t)PAD*4, stream);
  hipMemsetAsync(acc, 0, 448*4, stream);

  hipLaunchKernelGGL(k_w2b,     dim3(64),            dim3(256), 0, stream, l2fc, w2bp);
  hipLaunchKernelGGL(k_hist,    dim3((E+255)/256),   dim3(256), 0, stream, dstI, deg, E);
  hipLaunchKernelGGL(k_scan1,   dim3(B),             dim3(256), 0, stream, deg, part);
  hipLaunchKernelGGL(k_scan2,   dim3(1),             dim3(512), 0, stream, part, B);
  hipLaunchKernelGGL(k_scan3,   dim3(B),             dim3(256), 0, stream, deg, part, rowptr, cursor);
  hipLaunchKernelGGL(k_scatter, dim3((E+255)/256),   dim3(256), 0, stream, srcI, dstI, cursor, csr, E);
  hipLaunchKernelGGL(k_gemm1f,  dim3((N+63)/64),     dim3(256), 0, stream,
                     h, l1fc, l1at, zb, s1s, s1d, N);
  hipLaunchKernelGGL(k_gat1,    dim3((N+3)/4),       dim3(256), 0, stream,
                     zb, s1s, s1d, rowptr, csr, hneib, N);
  hipLaunchKernelGGL(k_gemm2,   dim3(((N+15)/16+3)/4), dim3(256), 0, stream,
                     (const ushort_t*)hneib, w2bp, l2at, z2b, s2s, s2d, N);
  hipLaunchKernelGGL(k_gat2,    dim3(1024),          dim3(256), 0, stream,
                     z2b, s2s, s2d, rowptr, csr, acc, N);
  hipLaunchKernelGGL(k_frac,    dim3(1024),          dim3(256), 0, stream, h, fcm, acc + 64, N);
  hipLaunchKernelGGL(k_finalize,dim3(1),             dim3(256), 0, stream,
                     acc, frw, frf, fc2, out, 1.0f/(float)N);
}

// Round 5
// 665.990 us; speedup vs baseline: 1.3992x; 1.1761x over previous
//
#include <hip/hip_runtime.h>
#include <math.h>

// GAT pipeline. bf16-packed z/hnei/z2; no-max softmax; both dense GEMMs on
// MFMA (GEMM1 uses split-A hi/lo bf16 for ~f32-quality A, W1 in bf16).

#define CAP 128   // per-wave LDS edge cache; deg>CAP falls back to recompute

typedef unsigned int  uint_t;
typedef unsigned short ushort_t;
typedef __attribute__((ext_vector_type(8))) short short8;
typedef __attribute__((ext_vector_type(4))) float floatx4;

__device__ __forceinline__ float wred_sum(float v){
#pragma unroll
  for (int o = 1; o < 64; o <<= 1) v += __shfl_xor(v, o, 64);
  return v;
}
__device__ __forceinline__ float lrelu(float x){ return x >= 0.f ? x : 0.01f*x; }
__device__ __forceinline__ ushort_t f2b(float f){
  uint_t u = __float_as_uint(f);
  u = (u + 0x7FFFu + ((u >> 16) & 1u)) >> 16;   // RNE
  return (ushort_t)u;
}
__device__ __forceinline__ float b2f_lo(uint_t w){ return __uint_as_float(w << 16); }
__device__ __forceinline__ float b2f_hi(uint_t w){ return __uint_as_float(w & 0xFFFF0000u); }

// ---------------- W1 pack into MFMA B-frag order (bf16):
// w1bp[((t*4+ks)*64 + lane)*8 + j] = bf16(W[(t*16+(lane&15))*128 + ks*32 + (lane>>4)*8 + j])
__global__ void k_w1b(const float* __restrict__ W, ushort_t* __restrict__ w1bp){
  int idx = blockIdx.x*256 + threadIdx.x;
  if (idx < 32768){
    int j = idx & 7, lane = (idx >> 3) & 63, ks = (idx >> 9) & 3, t = idx >> 11;
    int n = t*16 + (lane & 15), k = ks*32 + (lane >> 4)*8 + j;
    w1bp[idx] = f2b(W[n*128 + k]);
  }
}

// ---------------- GEMM1 (MFMA, split-A): zb[N][64] uint2 (4 heads bf16/dim) + layer1 scores
// Wave = one 16-row strip; 16 n-tiles cover all 256 cols; K=128 in 4 steps of 32.
__global__ __launch_bounds__(256) void k_gemm1m(const float* __restrict__ h,
    const ushort_t* __restrict__ w1bp, const float* __restrict__ a1,
    uint2* __restrict__ zb, float* __restrict__ s1s, float* __restrict__ s1d, int N)
{
  const int wave = threadIdx.x >> 6, lane = threadIdx.x & 63;
  const int quad = lane >> 4, l16 = lane & 15;
  const int row0 = blockIdx.x*64 + wave*16;
  if (row0 >= N) return;
  // per-lane score weights: dim d = m*16 + l16
  float a1sv[4][4], a1dv[4][4];
#pragma unroll
  for (int hh = 0; hh < 4; hh++)
#pragma unroll
    for (int m = 0; m < 4; m++){
      a1sv[hh][m] = a1[hh*128 + m*16 + l16];
      a1dv[hh][m] = a1[hh*128 + 64 + m*16 + l16];
    }
  const int ar = (row0 + l16 < N) ? (row0 + l16) : (N - 1);   // clamp; dup rows discarded
  floatx4 c[16];
#pragma unroll
  for (int t = 0; t < 16; t++) c[t] = (floatx4){0.f,0.f,0.f,0.f};
#pragma unroll
  for (int ks = 0; ks < 4; ks++){
    const float* ap = &h[(size_t)ar*128 + ks*32 + quad*8];
    float4 v0 = *(const float4*)ap;
    float4 v1 = *(const float4*)(ap + 4);
    float vv[8] = {v0.x,v0.y,v0.z,v0.w,v1.x,v1.y,v1.z,v1.w};
    short8 ahi, alo;
#pragma unroll
    for (int j = 0; j < 8; j++){
      ushort_t hb = f2b(vv[j]);
      float hf = __uint_as_float((uint_t)hb << 16);
      ahi[j] = (short)hb;
      alo[j] = (short)f2b(vv[j] - hf);
    }
#pragma unroll
    for (int t = 0; t < 16; t++){
      short8 b = *(const short8*)&w1bp[(size_t)((t*4 + ks)*64 + lane)*8];
      c[t] = __builtin_amdgcn_mfma_f32_16x16x32_bf16(ahi, b, c[t], 0, 0, 0);
      c[t] = __builtin_amdgcn_mfma_f32_16x16x32_bf16(alo, b, c[t], 0, 0, 0);
    }
  }
  // epilogue: C layout col = t*16 + l16, row = row0 + quad*4 + i
#pragma unroll
  for (int i = 0; i < 4; i++){
    const int r = row0 + quad*4 + i;
    if (r >= N) continue;
#pragma unroll
    for (int m = 0; m < 4; m++){
      uint_t w0 = (uint_t)f2b(c[0*4+m][i]) | ((uint_t)f2b(c[1*4+m][i]) << 16);
      uint_t w1 = (uint_t)f2b(c[2*4+m][i]) | ((uint_t)f2b(c[3*4+m][i]) << 16);
      zb[(size_t)r*64 + m*16 + l16] = make_uint2(w0, w1);
    }
#pragma unroll
    for (int hh = 0; hh < 4; hh++){
      float ps = 0.f, pd = 0.f;
#pragma unroll
      for (int m = 0; m < 4; m++){
        float v = c[hh*4+m][i];
        ps += v * a1sv[hh][m];
        pd += v * a1dv[hh][m];
      }
#pragma unroll
      for (int o = 1; o < 16; o <<= 1){
        ps += __shfl_xor(ps, o, 64);
        pd += __shfl_xor(pd, o, 64);
      }
      if (l16 == 0){ s1s[r*4+hh] = ps; s1d[r*4+hh] = pd; }
    }
  }
}

// ---------------- CSR build
__global__ void k_hist(const int* __restrict__ d, int* __restrict__ deg, int E){
  int i = blockIdx.x*256 + threadIdx.x;
  if (i < E) atomicAdd(&deg[d[i]], 1);
}
__global__ __launch_bounds__(256) void k_scan1(const int* __restrict__ deg, int* __restrict__ part){
  __shared__ int tmp[256];
  int t = threadIdx.x;
  tmp[t] = deg[blockIdx.x*256 + t];
  __syncthreads();
  for (int off = 128; off > 0; off >>= 1){
    if (t < off) tmp[t] += tmp[t+off];
    __syncthreads();
  }
  if (t == 0) part[blockIdx.x] = tmp[0];
}
__global__ __launch_bounds__(512) void k_scan2(int* __restrict__ part, int B){
  __shared__ int tmp[512];
  int t = threadIdx.x;
  int v = (t < B) ? part[t] : 0;
  tmp[t] = v; __syncthreads();
  for (int off = 1; off < 512; off <<= 1){
    int x = (t >= off) ? tmp[t-off] : 0;
    __syncthreads();
    tmp[t] += x;
    __syncthreads();
  }
  if (t < B) part[t] = tmp[t] - v;   // exclusive
}
__global__ __launch_bounds__(256) void k_scan3(const int* __restrict__ deg, const int* __restrict__ part,
    int* __restrict__ rowptr, int* __restrict__ cursor){
  __shared__ int tmp[256];
  int t = threadIdx.x, i = blockIdx.x*256 + t;
  int v = deg[i];
  tmp[t] = v; __syncthreads();
  for (int off = 1; off < 256; off <<= 1){
    int x = (t >= off) ? tmp[t-off] : 0;
    __syncthreads();
    tmp[t] += x;
    __syncthreads();
  }
  int excl = tmp[t] - v + part[blockIdx.x];
  rowptr[i] = excl; cursor[i] = excl;
}
__global__ void k_scatter(const int* __restrict__ s, const int* __restrict__ d,
    int* __restrict__ cursor, int* __restrict__ csr, int E){
  int i = blockIdx.x*256 + threadIdx.x;
  if (i < E){
    int p = atomicAdd(&cursor[d[i]], 1);
    csr[p] = s[i];
  }
}

// ---------------- W2 pack into MFMA B-frag order
__global__ void k_w2b(const float* __restrict__ fc, ushort_t* __restrict__ w2bp){
  int idx = blockIdx.x*256 + threadIdx.x;
  if (idx < 16384){
    int j = idx & 7, lane = (idx >> 3) & 63, ks = (idx >> 9) & 7, t = idx >> 12;
    int n = t*16 + (lane & 15), k = ks*32 + (lane >> 4)*8 + j;
    w2bp[idx] = f2b(fc[n*256 + k]);
  }
}

// ---------------- layer1 GAT edge aggregation + ELU -> hneib [N,256] bf16
__global__ __launch_bounds__(256) void k_gat1(
    const uint2* __restrict__ zb, const float* __restrict__ s1src, const float* __restrict__ s1dst,
    const int* __restrict__ rowptr, const int* __restrict__ csr,
    uint_t* __restrict__ hneib, int N)
{
  __shared__ int   sbuf[4][CAP];
  __shared__ __align__(16) float4 ebuf[4][CAP];
  const int wave = threadIdx.x >> 6, lane = threadIdx.x & 63;
  const int dst = blockIdx.x*4 + wave;
  if (dst >= N) return;
  const int beg = rowptr[dst];
  const int deg = rowptr[dst+1] - beg;
  const float4 sd = *(const float4*)&s1dst[dst*4];
  float t0=0.f,t1=0.f,t2=0.f,t3=0.f;
  for (int j = lane; j < deg; j += 64){
    int s = csr[beg+j];
    float4 sv = *(const float4*)&s1src[s*4];
    float4 a;
    a.x = __expf(lrelu(sv.x+sd.x)); a.y = __expf(lrelu(sv.y+sd.y));
    a.z = __expf(lrelu(sv.z+sd.z)); a.w = __expf(lrelu(sv.w+sd.w));
    if (j < CAP){ sbuf[wave][j] = s; ebuf[wave][j] = a; }
    t0 += a.x; t1 += a.y; t2 += a.z; t3 += a.w;
  }
  const float i0 = 1.f/wred_sum(t0), i1 = 1.f/wred_sum(t1);
  const float i2 = 1.f/wred_sum(t2), i3 = 1.f/wred_sum(t3);
  const int eh = lane >> 5, li = lane & 31;
  float acc[2][4] = {};
  int jj = 0;
  if (deg <= CAP){
    for (; jj + 2 <= deg; jj += 2){
      const int j = jj + eh;
      int s = sbuf[wave][j]; float4 al = ebuf[wave][j];
      uint4 u = *((const uint4*)(zb + (size_t)s*64) + li);
      acc[0][0] += al.x * b2f_lo(u.x);
      acc[0][1] += al.y * b2f_hi(u.x);
      acc[0][2] += al.z * b2f_lo(u.y);
      acc[0][3] += al.w * b2f_hi(u.y);
      acc[1][0] += al.x * b2f_lo(u.z);
      acc[1][1] += al.y * b2f_hi(u.z);
      acc[1][2] += al.z * b2f_lo(u.w);
      acc[1][3] += al.w * b2f_hi(u.w);
    }
    if (jj < deg && eh == 0){
      int s = sbuf[wave][jj]; float4 al = ebuf[wave][jj];
      uint4 u = *((const uint4*)(zb + (size_t)s*64) + li);
      acc[0][0] += al.x * b2f_lo(u.x);
      acc[0][1] += al.y * b2f_hi(u.x);
      acc[0][2] += al.z * b2f_lo(u.y);
      acc[0][3] += al.w * b2f_hi(u.y);
      acc[1][0] += al.x * b2f_lo(u.z);
      acc[1][1] += al.y * b2f_hi(u.z);
      acc[1][2] += al.z * b2f_lo(u.w);
      acc[1][3] += al.w * b2f_hi(u.w);
    }
  } else {
    for (; jj < deg; jj += 2){
      const int j = jj + eh;
      const bool v = j < deg;
      const int jc = v ? j : jj;
      int s; float4 al;
      if (jc < CAP){ s = sbuf[wave][jc]; al = ebuf[wave][jc]; }
      else {
        s = csr[beg+jc];
        float4 sv = *(const float4*)&s1src[s*4];
        al.x = __expf(lrelu(sv.x+sd.x)); al.y = __expf(lrelu(sv.y+sd.y));
        al.z = __expf(lrelu(sv.z+sd.z)); al.w = __expf(lrelu(sv.w+sd.w));
      }
      if (!v){ al.x = 0.f; al.y = 0.f; al.z = 0.f; al.w = 0.f; }
      uint4 u = *((const uint4*)(zb + (size_t)s*64) + li);
      acc[0][0] += al.x * b2f_lo(u.x);
      acc[0][1] += al.y * b2f_hi(u.x);
      acc[0][2] += al.z * b2f_lo(u.y);
      acc[0][3] += al.w * b2f_hi(u.y);
      acc[1][0] += al.x * b2f_lo(u.z);
      acc[1][1] += al.y * b2f_hi(u.z);
      acc[1][2] += al.z * b2f_lo(u.w);
      acc[1][3] += al.w * b2f_hi(u.w);
    }
  }
#pragma unroll
  for (int k = 0; k < 2; k++)
#pragma unroll
    for (int hh = 0; hh < 4; hh++) acc[k][hh] += __shfl_xor(acc[k][hh], 32, 64);
  if (eh == 0){
    const float inv[4] = {i0, i1, i2, i3};
#pragma unroll
    for (int hh = 0; hh < 4; hh++){
      float v0 = acc[0][hh]*inv[hh]; v0 = v0 > 0.f ? v0 : expm1f(v0);
      float v1 = acc[1][hh]*inv[hh]; v1 = v1 > 0.f ? v1 : expm1f(v1);
      hneib[(size_t)dst*128 + hh*32 + li] = (uint_t)f2b(v0) | ((uint_t)f2b(v1) << 16);
    }
  }
}

// ---------------- GEMM2 (MFMA bf16): z2 = hnei @ W2^T, fused scores + bf16 store
__global__ __launch_bounds__(256) void k_gemm2(
    const ushort_t* __restrict__ hneib, const ushort_t* __restrict__ w2bp,
    const float* __restrict__ a2w,
    ushort_t* __restrict__ z2b, float* __restrict__ s2s, float* __restrict__ s2d, int N)
{
  const int wave = threadIdx.x >> 6, lane = threadIdx.x & 63;
  const int quad = lane >> 4, l16 = lane & 15;
  const int strip = blockIdx.x*4 + wave;
  const int nstrips = (N + 15) >> 4;
  if (strip >= nstrips) return;
  const int row0 = strip * 16;
  float a2s[4], a2d[4];
#pragma unroll
  for (int t = 0; t < 4; t++){
    a2s[t] = a2w[t*16 + l16];
    a2d[t] = a2w[64 + t*16 + l16];
  }
  const int ar = (row0 + l16 < N) ? (row0 + l16) : (N - 1);
  floatx4 c[4] = {{0.f,0.f,0.f,0.f},{0.f,0.f,0.f,0.f},{0.f,0.f,0.f,0.f},{0.f,0.f,0.f,0.f}};
#pragma unroll
  for (int ks = 0; ks < 8; ks++){
    short8 a = *(const short8*)&hneib[(size_t)ar*256 + ks*32 + quad*8];
#pragma unroll
    for (int t = 0; t < 4; t++){
      short8 b = *(const short8*)&w2bp[(size_t)((t*8 + ks)*64 + lane)*8];
      c[t] = __builtin_amdgcn_mfma_f32_16x16x32_bf16(a, b, c[t], 0, 0, 0);
    }
  }
#pragma unroll
  for (int i = 0; i < 4; i++){
    const int r = row0 + quad*4 + i;
    float ps = 0.f, pd = 0.f;
    if (r < N){
#pragma unroll
      for (int t = 0; t < 4; t++){
        float v = c[t][i];
        z2b[(size_t)r*64 + t*16 + l16] = f2b(v);
        ps += v * a2s[t]; pd += v * a2d[t];
      }
#pragma unroll
      for (int o = 1; o < 16; o <<= 1){
        ps += __shfl_xor(ps, o, 64);
        pd += __shfl_xor(pd, o, 64);
      }
      if (l16 == 0){ s2s[r] = ps; s2d[r] = pd; }
    }
  }
}

// ---------------- layer2 GAT, reduced straight to the global sum
__global__ __launch_bounds__(256) void k_gat2(
    const ushort_t* __restrict__ z2b, const float* __restrict__ s2src, const float* __restrict__ s2dst,
    const int* __restrict__ rowptr, const int* __restrict__ csr,
    float* __restrict__ accOut, int N)
{
  __shared__ int   sbuf[4][CAP];
  __shared__ float ebuf[4][CAP];
  __shared__ __align__(16) float red[4][64];
  const int wave = threadIdx.x >> 6, lane = threadIdx.x & 63;
  const int g4 = lane >> 4, li = lane & 15;
  float g0=0.f, g1=0.f, g2=0.f, g3=0.f;
  const int stride = gridDim.x * 4;
  for (int dst = blockIdx.x*4 + wave; dst < N; dst += stride){
    const int beg = rowptr[dst], deg = rowptr[dst+1] - beg;
    const float sd = s2dst[dst];
    float ts = 0.f;
    for (int j = lane; j < deg; j += 64){
      int s = csr[beg+j];
      float a = __expf(lrelu(s2src[s] + sd));
      if (j < CAP){ sbuf[wave][j] = s; ebuf[wave][j] = a; }
      ts += a;
    }
    const float inv = 1.f/wred_sum(ts);
    float c0=0.f, c1=0.f, c2=0.f, c3=0.f;
    int jj = 0;
    if (deg <= CAP){
      for (; jj + 4 <= deg; jj += 4){
        const int j = jj + g4;
        int s = sbuf[wave][j]; float al = ebuf[wave][j];
        uint2 u = *((const uint2*)(z2b + (size_t)s*64) + li);
        c0 += al * b2f_lo(u.x);
        c1 += al * b2f_hi(u.x);
        c2 += al * b2f_lo(u.y);
        c3 += al * b2f_hi(u.y);
      }
      if (jj < deg && g4 < deg - jj){
        const int j = jj + g4;
        int s = sbuf[wave][j]; float al = ebuf[wave][j];
        uint2 u = *((const uint2*)(z2b + (size_t)s*64) + li);
        c0 += al * b2f_lo(u.x);
        c1 += al * b2f_hi(u.x);
        c2 += al * b2f_lo(u.y);
        c3 += al * b2f_hi(u.y);
      }
    } else {
      for (; jj < deg; jj += 4){
        const int j = jj + g4;
        const bool v = j < deg;
        const int jc = v ? j : jj;
        int s; float al;
        if (jc < CAP){ s = sbuf[wave][jc]; al = ebuf[wave][jc]; }
        else { s = csr[beg+jc]; al = __expf(lrelu(s2src[s] + sd)); }
        if (!v) al = 0.f;
        uint2 u = *((const uint2*)(z2b + (size_t)s*64) + li);
        c0 += al * b2f_lo(u.x);
        c1 += al * b2f_hi(u.x);
        c2 += al * b2f_lo(u.y);
        c3 += al * b2f_hi(u.y);
      }
    }
    c0 += __shfl_xor(c0,16,64); c0 += __shfl_xor(c0,32,64);
    c1 += __shfl_xor(c1,16,64); c1 += __shfl_xor(c1,32,64);
    c2 += __shfl_xor(c2,16,64); c2 += __shfl_xor(c2,32,64);
    c3 += __shfl_xor(c3,16,64); c3 += __shfl_xor(c3,32,64);
    g0 += inv*c0; g1 += inv*c1; g2 += inv*c2; g3 += inv*c3;
  }
  if (g4 == 0) *(float4*)&red[wave][li*4] = make_float4(g0,g1,g2,g3);
  __syncthreads();
  if (wave == 0)
    atomicAdd(&accOut[lane], red[0][lane]+red[1][lane]+red[2][lane]+red[3][lane]);
}

// ---------------- fractal: acc[s][k] = sum_n h[fcm[n,s]][k]   (exact f32)
__global__ __launch_bounds__(256) void k_frac(const float* __restrict__ h,
    const int* __restrict__ fcm, float* __restrict__ accFrac, int N)
{
  __shared__ float red[4][6][64];
  const int wave = threadIdx.x >> 6, lane = threadIdx.x & 63;
  float a[6] = {0.f,0.f,0.f,0.f,0.f,0.f};
  const int stride = gridDim.x * 4;
  for (int n = blockIdx.x*4 + wave; n < N; n += stride){
    int i0 = fcm[n*3], i1 = fcm[n*3+1], i2 = fcm[n*3+2];
    a[0] += h[(size_t)i0*128 + lane]; a[1] += h[(size_t)i0*128 + 64 + lane];
    a[2] += h[(size_t)i1*128 + lane]; a[3] += h[(size_t)i1*128 + 64 + lane];
    a[4] += h[(size_t)i2*128 + lane]; a[5] += h[(size_t)i2*128 + 64 + lane];
  }
#pragma unroll
  for (int q = 0; q < 6; q++) red[wave][q][lane] = a[q];
  __syncthreads();
  if (wave == 0){
#pragma unroll
    for (int q = 0; q < 6; q++){
      float v = red[0][q][lane]+red[1][q][lane]+red[2][q][lane]+red[3][q][lane];
      atomicAdd(&accFrac[(q>>1)*128 + (q&1)*64 + lane], v);
    }
  }
}

// ---------------- finalize
__global__ __launch_bounds__(256) void k_finalize(const float* __restrict__ acc,
    const float* __restrict__ frw, const float* __restrict__ frf,
    const float* __restrict__ fc2, float* __restrict__ out, float invN)
{
  __shared__ float g[384], mm[192], hfrac[64], nei[64];
  int t = threadIdx.x;
  for (int i = t; i < 384; i += 256) g[i] = acc[64 + i] * invN;
  if (t < 64) nei[t] = acc[t] * invN;
  __syncthreads();
  for (int i = t; i < 192; i += 256){
    int s = i >> 6, d = i & 63;
    const float* w = frw + (size_t)(s*64 + d)*128;
    const float* gs = g + s*128;
    float sum = 0.f;
    for (int k = 0; k < 128; k++) sum += gs[k]*w[k];
    mm[i] = sum;
  }
  __syncthreads();
  if (t < 64){
    float s = 0.f;
    for (int k = 0; k < 192; k++) s += mm[k]*frf[t*192 + k];
    hfrac[t] = s;
  }
  __syncthreads();
  if (t < 64){
    float o = 0.f;
    for (int k = 0; k < 64; k++)
      o += fc2[t*128 + k]*nei[k] + fc2[t*128 + 64 + k]*hfrac[k];
    out[t] = o;
  }
}

extern "C" void kernel_launch(void* const* d_in, const int* in_sizes, int n_in,
                              void* d_out, int out_size, void* d_ws, size_t ws_size,
                              hipStream_t stream)
{
  const float* h    = (const float*)d_in[0];
  const int*   srcI = (const int*)  d_in[1];
  const int*   dstI = (const int*)  d_in[2];
  const int*   fcm  = (const int*)  d_in[3];
  const float* l1fc = (const float*)d_in[4];
  const float* l1at = (const float*)d_in[5];
  const float* l2fc = (const float*)d_in[6];
  const float* l2at = (const float*)d_in[7];
  const float* frw  = (const float*)d_in[8];
  const float* frf  = (const float*)d_in[9];
  const float* fc2  = (const float*)d_in[10];
  float* out = (float*)d_out;
  (void)n_in; (void)out_size; (void)ws_size;

  const int N = in_sizes[0] / 128;
  const int E = in_sizes[1];
  const int B = (N + 256) / 256;     // ceil((N+1)/256) so rowptr[N] is covered
  const int PAD = B * 256;

  char* w = (char*)d_ws;
  size_t off = 0;
  auto alloc = [&](size_t bytes) -> char* {
    char* p = w + off; off = (off + bytes + 255) & ~(size_t)255; return p;
  };
  uint2*    zb    = (uint2*)   alloc((size_t)N*64*8);   // 51.2 MB packed bf16 z
  uint_t*   hneib = (uint_t*)  alloc((size_t)N*128*4);  // 51.2 MB packed bf16 hnei [N,256]
  ushort_t* z2b   = (ushort_t*)alloc((size_t)N*64*2);   // 12.8 MB bf16 z2
  float* s1s  = (float*)alloc((size_t)N*4*4);
  float* s1d  = (float*)alloc((size_t)N*4*4);
  float* s2s  = (float*)alloc((size_t)N*4);
  float* s2d  = (float*)alloc((size_t)N*4);
  int*   deg    = (int*)alloc((size_t)PAD*4);
  int*   rowptr = (int*)alloc((size_t)PAD*4);
  int*   cursor = (int*)alloc((size_t)PAD*4);
  int*   part   = (int*)alloc(512*4);
  int*   csr    = (int*)alloc((size_t)E*4);
  ushort_t* w1bp = (ushort_t*)alloc(32768*2);
  ushort_t* w2bp = (ushort_t*)alloc(16384*2);
  float* acc    = (float*)alloc(448*4);   // [0:64) nei2-sum, [64:448) frac-sum

  hipMemsetAsync(deg, 0, (size_t)PAD*4, stream);
  hipMemsetAsync(acc, 0, 448*4, stream);

  hipLaunchKernelGGL(k_w1b,     dim3(128),           dim3(256), 0, stream, l1fc, w1bp);
  hipLaunchKernelGGL(k_w2b,     dim3(64),            dim3(256), 0, stream, l2fc, w2bp);
  hipLaunchKernelGGL(k_hist,    dim3((E+255)/256),   dim3(256), 0, stream, dstI, deg, E);
  hipLaunchKernelGGL(k_scan1,   dim3(B),             dim3(256), 0, stream, deg, part);
  hipLaunchKernelGGL(k_scan2,   dim3(1),             dim3(512), 0, stream, part, B);
  hipLaunchKernelGGL(k_scan3,   dim3(B),             dim3(256), 0, stream, deg, part, rowptr, cursor);
  hipLaunchKernelGGL(k_scatter, dim3((E+255)/256),   dim3(256), 0, stream, srcI, dstI, cursor, csr, E);
  hipLaunchKernelGGL(k_gemm1m,  dim3((N+63)/64),     dim3(256), 0, stream,
                     h, w1bp, l1at, zb, s1s, s1d, N);
  hipLaunchKernelGGL(k_gat1,    dim3((N+3)/4),       dim3(256), 0, stream,
                     zb, s1s, s1d, rowptr, csr, hneib, N);
  hipLaunchKernelGGL(k_gemm2,   dim3(((N+15)/16+3)/4), dim3(256), 0, stream,
                     (const ushort_t*)hneib, w2bp, l2at, z2b, s2s, s2d, N);
  hipLaunchKernelGGL(k_gat2,    dim3(1024),          dim3(256), 0, stream,
                     z2b, s2s, s2d, rowptr, csr, acc, N);
  hipLaunchKernelGGL(k_frac,    dim3(1024),          dim3(256), 0, stream, h, fcm, acc + 64, N);
  hipLaunchKernelGGL(k_finalize,dim3(1),             dim3(256), 0, stream,
                     acc, frw, frf, fc2, out, 1.0f/(float)N);
}